// Round 1
// baseline (579.919 us; speedup 1.0000x reference)
//
#include <hip/hip_runtime.h>
#include <hip/hip_bf16.h>

// Problem constants (from reference)
#define NN 2048
#define TT 64
#define EE 16384
#define BB 64
#define K0C 32
#define EMBC 128
#define K1C 64
#define K2C 64
#define KSZ 7
#define POOLK 4
#define BNEPS 1e-5f

// ---------------------------------------------------------------------------
// Graph preprocessing: degree count, dinv, exclusive scan, CSR fill
// ---------------------------------------------------------------------------
__global__ void count_deg_kernel(const int* __restrict__ ei, int* __restrict__ deg) {
    int e = blockIdx.x * 256 + threadIdx.x;
    if (e < EE) atomicAdd(&deg[ei[EE + e]], 1);   // dst = second row
}

__global__ void dinv_kernel(const int* __restrict__ deg, float* __restrict__ dinv) {
    int n = blockIdx.x * 256 + threadIdx.x;
    if (n < NN) dinv[n] = rsqrtf((float)deg[n] + 1.0f);   // +1 self loop
}

// Exclusive scan of deg[0..N) -> row_start[0..N], single block of 256, 8 elems/thread
__global__ void scan_kernel(const int* __restrict__ deg, int* __restrict__ row_start) {
    __shared__ int tsum[256];
    int tid = threadIdx.x;
    int loc[8];
    int s = 0;
#pragma unroll
    for (int i = 0; i < 8; ++i) { loc[i] = s; s += deg[tid * 8 + i]; }
    tsum[tid] = s;
    __syncthreads();
    for (int off = 1; off < 256; off <<= 1) {
        int v = (tid >= off) ? tsum[tid - off] : 0;
        __syncthreads();
        tsum[tid] += v;
        __syncthreads();
    }
    int base = (tid > 0) ? tsum[tid - 1] : 0;
#pragma unroll
    for (int i = 0; i < 8; ++i) row_start[tid * 8 + i] = base + loc[i];
    if (tid == 255) row_start[NN] = tsum[255];
}

__global__ void fill_csr_kernel(const int* __restrict__ ei, const int* __restrict__ row_start,
                                int* __restrict__ cursor, const float* __restrict__ dinv,
                                int* __restrict__ csr_src, float* __restrict__ csr_norm) {
    int e = blockIdx.x * 256 + threadIdx.x;
    if (e >= EE) return;
    int s = ei[e];
    int d = ei[EE + e];
    int pos = row_start[d] + atomicAdd(&cursor[d], 1);
    csr_src[pos] = s;
    csr_norm[pos] = dinv[s] * dinv[d];
}

// ---------------------------------------------------------------------------
// conv1 (SAME, 1->32) + bn1 + relu : x (N,T) -> h0 (N,T,32)
// ---------------------------------------------------------------------------
__global__ void conv1_bn_relu_kernel(const float* __restrict__ x, const float* __restrict__ w,
                                     const float* __restrict__ g, const float* __restrict__ b,
                                     const float* __restrict__ m, const float* __restrict__ v,
                                     float* __restrict__ h0) {
    int idx = blockIdx.x * 256 + threadIdx.x;      // N*T*32 total
    int c = idx & 31;
    int t = (idx >> 5) & 63;
    int n = idx >> 11;
    float acc = 0.f;
#pragma unroll
    for (int k = 0; k < KSZ; ++k) {
        int tt = t + k - 3;
        if (tt >= 0 && tt < TT) acc += x[n * TT + tt] * w[k * K0C + c];
    }
    float scale = g[c] * rsqrtf(v[c] + BNEPS);
    float val = (acc - m[c]) * scale + b[c];
    h0[idx] = fmaxf(val, 0.f);
}

// ---------------------------------------------------------------------------
// Aggregation: out[n] = dinv[n]^2 * h[n] + sum_e norm_e * h[src_e], per-node gather
// h layout: (N, T*C) contiguous. One block per node, 256 threads, float4 lanes.
// ---------------------------------------------------------------------------
template <int C>
__global__ __launch_bounds__(256) void aggregate_kernel(
        const float* __restrict__ h, float* __restrict__ out,
        const int* __restrict__ row_start, const int* __restrict__ csr_src,
        const float* __restrict__ csr_norm, const float* __restrict__ dinv) {
    constexpr int TC = TT * C;
    constexpr int V = TC / (4 * 256);     // float4 per thread (C=32 -> 2, C=128 -> 8)
    __shared__ int s_src[256];
    __shared__ float s_w[256];
    int n = blockIdx.x;
    int tid = threadIdx.x;
    int rs = row_start[n], re = row_start[n + 1];
    float dn = dinv[n];
    float selfw = dn * dn;
    const float4* hn = (const float4*)(h + (size_t)n * TC);
    float4 acc[V];
#pragma unroll
    for (int vv = 0; vv < V; ++vv) {
        float4 xv = hn[tid + vv * 256];
        acc[vv] = make_float4(selfw * xv.x, selfw * xv.y, selfw * xv.z, selfw * xv.w);
    }
    for (int e0 = rs; e0 < re; e0 += 256) {
        int cnt = min(256, re - e0);
        if (tid < cnt) { s_src[tid] = csr_src[e0 + tid]; s_w[tid] = csr_norm[e0 + tid]; }
        __syncthreads();
        for (int j = 0; j < cnt; ++j) {
            const float4* hs = (const float4*)(h + (size_t)s_src[j] * TC);
            float wgt = s_w[j];
#pragma unroll
            for (int vv = 0; vv < V; ++vv) {
                float4 xv = hs[tid + vv * 256];
                acc[vv].x += wgt * xv.x; acc[vv].y += wgt * xv.y;
                acc[vv].z += wgt * xv.z; acc[vv].w += wgt * xv.w;
            }
        }
        __syncthreads();
    }
    float4* o = (float4*)(out + (size_t)n * TC);
#pragma unroll
    for (int vv = 0; vv < V; ++vv) o[tid + vv * 256] = acc[vv];
}

// ---------------------------------------------------------------------------
// GEMM: C = relu(A(M,K) @ W(K,128) + bias). Block: 64 rows x 128 cols,
// 256 threads, each 8x4 register tile. K in {32,128}.
// ---------------------------------------------------------------------------
template <int K>
__global__ __launch_bounds__(256) void gemm_bias_relu_kernel(
        const float* __restrict__ A, const float* __restrict__ W,
        const float* __restrict__ bias, float* __restrict__ C) {
    __shared__ float sA[64 * 32];
    __shared__ float sB[32 * 128];
    const int tid = threadIdx.x;
    const int tx = tid & 31;        // col quad: c0 = tx*4
    const int ty = tid >> 5;        // rows ty*8 .. ty*8+7
    const size_t m0 = (size_t)blockIdx.x * 64;
    float acc[8][4];
#pragma unroll
    for (int r = 0; r < 8; ++r)
#pragma unroll
        for (int c = 0; c < 4; ++c) acc[r][c] = 0.f;

    for (int kk = 0; kk < K; kk += 32) {
#pragma unroll
        for (int i = tid; i < 512; i += 256) {       // A tile 64x32 as float4
            int r = i >> 3, kq = i & 7;
            *(float4*)&sA[r * 32 + kq * 4] = *(const float4*)(A + (m0 + r) * K + kk + kq * 4);
        }
#pragma unroll
        for (int i = tid; i < 1024; i += 256) {      // W tile 32x128 as float4
            int r = i >> 5, cq = i & 31;
            *(float4*)&sB[r * 128 + cq * 4] = *(const float4*)(W + (size_t)(kk + r) * 128 + cq * 4);
        }
        __syncthreads();
#pragma unroll
        for (int k = 0; k < 32; ++k) {
            float4 bv = *(const float4*)&sB[k * 128 + tx * 4];
#pragma unroll
            for (int r = 0; r < 8; ++r) {
                float a = sA[(ty * 8 + r) * 32 + k];
                acc[r][0] += a * bv.x; acc[r][1] += a * bv.y;
                acc[r][2] += a * bv.z; acc[r][3] += a * bv.w;
            }
        }
        __syncthreads();
    }
    float4 biasv = *(const float4*)(bias + tx * 4);
#pragma unroll
    for (int r = 0; r < 8; ++r) {
        float4 o;
        o.x = fmaxf(acc[r][0] + biasv.x, 0.f);
        o.y = fmaxf(acc[r][1] + biasv.y, 0.f);
        o.z = fmaxf(acc[r][2] + biasv.z, 0.f);
        o.w = fmaxf(acc[r][3] + biasv.w, 0.f);
        *(float4*)(C + (m0 + ty * 8 + r) * 128 + tx * 4) = o;
    }
}

// ---------------------------------------------------------------------------
// conv2 (VALID, 128->64, T 64->58) + bn2 + avgpool4 (->14) + relu, fused.
// One block per node. h2 row staged in LDS (stride 132 kills bank conflicts).
// Thread = (pool group g in 0..13, c quad) -> 4t x 4c register tile, pooled.
// ---------------------------------------------------------------------------
__global__ __launch_bounds__(256) void conv2_fused_kernel(
        const float* __restrict__ h2, const float* __restrict__ w2,
        const float* __restrict__ g2, const float* __restrict__ b2,
        const float* __restrict__ m2, const float* __restrict__ v2,
        float* __restrict__ h3) {
    __shared__ float sh[64 * 132];
    int n = blockIdx.x;
    int tid = threadIdx.x;
    const float4* src = (const float4*)(h2 + (size_t)n * TT * EMBC);
    for (int i = tid; i < 2048; i += 256) {
        int t = i >> 5, cq = i & 31;
        *(float4*)&sh[t * 132 + cq * 4] = src[i];
    }
    __syncthreads();
    if (tid >= 224) return;            // 14 groups x 16 c-quads
    int g = tid / 16;
    int c0 = (tid % 16) * 4;
    float acc[4][4];
#pragma unroll
    for (int j = 0; j < 4; ++j)
#pragma unroll
        for (int c = 0; c < 4; ++c) acc[j][c] = 0.f;
#pragma unroll
    for (int k = 0; k < KSZ; ++k) {
        int tbase = 4 * g + k;
        for (int cin = 0; cin < EMBC; ++cin) {
            float4 wv = *(const float4*)(w2 + ((size_t)(k * EMBC + cin)) * K1C + c0);
#pragma unroll
            for (int j = 0; j < 4; ++j) {
                float hv = sh[(tbase + j) * 132 + cin];
                acc[j][0] += hv * wv.x; acc[j][1] += hv * wv.y;
                acc[j][2] += hv * wv.z; acc[j][3] += hv * wv.w;
            }
        }
    }
#pragma unroll
    for (int cc = 0; cc < 4; ++cc) {
        int c = c0 + cc;
        float p = 0.25f * (acc[0][cc] + acc[1][cc] + acc[2][cc] + acc[3][cc]);
        float scale = g2[c] * rsqrtf(v2[c] + BNEPS);
        float val = (p - m2[c]) * scale + b2[c];
        h3[((size_t)n * 14 + g) * K1C + c] = fmaxf(val, 0.f);
    }
}

// ---------------------------------------------------------------------------
// Global mean pool per graph: h3 (N,14,64) -> g1 (B,14,64). batch = n/32
// (input `batch` is arange(N)//32 by construction).
// ---------------------------------------------------------------------------
__global__ void graph_pool_kernel(const float* __restrict__ h3, float* __restrict__ g1) {
    int b = blockIdx.x;
    for (int i = threadIdx.x; i < 14 * K1C; i += 256) {
        float acc = 0.f;
        for (int nn = 0; nn < 32; ++nn)
            acc += h3[((size_t)(b * 32 + nn)) * (14 * K1C) + i];
        g1[(size_t)b * (14 * K1C) + i] = acc * (1.f / 32.f);
    }
}

// ---------------------------------------------------------------------------
// Head: conv3 (VALID 14->8, 64->64) + bn3 + pool4 (->2) + relu + flatten(128)
//       + dense(128->4) + log_softmax. One block per graph.
// ---------------------------------------------------------------------------
__global__ __launch_bounds__(256) void head_kernel(
        const float* __restrict__ g1, const float* __restrict__ w3,
        const float* __restrict__ g3, const float* __restrict__ b3,
        const float* __restrict__ m3, const float* __restrict__ v3,
        const float* __restrict__ dw, const float* __restrict__ db,
        float* __restrict__ out) {
    __shared__ float sg[14 * 64];
    __shared__ float sconv[8 * 64];
    __shared__ float sflat[128];
    __shared__ float slog[4];
    int b = blockIdx.x;
    int tid = threadIdx.x;
    for (int i = tid; i < 14 * 64; i += 256) sg[i] = g1[(size_t)b * (14 * 64) + i];
    __syncthreads();
    for (int i = tid; i < 8 * 64; i += 256) {
        int t = i >> 6, c = i & 63;
        float acc = 0.f;
        for (int k = 0; k < KSZ; ++k)
            for (int cin = 0; cin < 64; ++cin)
                acc += sg[(t + k) * 64 + cin] * w3[((size_t)(k * 64 + cin)) * 64 + c];
        sconv[i] = acc;
    }
    __syncthreads();
    for (int i = tid; i < 128; i += 256) {
        int j = i >> 6, c = i & 63;
        float p = 0.25f * (sconv[(4 * j + 0) * 64 + c] + sconv[(4 * j + 1) * 64 + c] +
                           sconv[(4 * j + 2) * 64 + c] + sconv[(4 * j + 3) * 64 + c]);
        float scale = g3[c] * rsqrtf(v3[c] + BNEPS);
        float val = (p - m3[c]) * scale + b3[c];
        sflat[i] = fmaxf(val, 0.f);
    }
    __syncthreads();
    if (tid < 4) {
        float acc = db[tid];
        for (int i = 0; i < 128; ++i) acc += sflat[i] * dw[i * 4 + tid];
        slog[tid] = acc;
    }
    __syncthreads();
    if (tid < 4) {
        float mx = fmaxf(fmaxf(slog[0], slog[1]), fmaxf(slog[2], slog[3]));
        float s = expf(slog[0] - mx) + expf(slog[1] - mx) +
                  expf(slog[2] - mx) + expf(slog[3] - mx);
        out[b * 4 + tid] = slog[tid] - mx - logf(s);
    }
}

// ---------------------------------------------------------------------------
extern "C" void kernel_launch(void* const* d_in, const int* in_sizes, int n_in,
                              void* d_out, int out_size, void* d_ws, size_t ws_size,
                              hipStream_t stream) {
    const float* x       = (const float*)d_in[0];
    const int*   ei      = (const int*)d_in[1];
    // d_in[2] = batch (arange//32, handled analytically)
    const float* conv1_w = (const float*)d_in[3];
    const float* bn1_g   = (const float*)d_in[4];
    const float* bn1_b   = (const float*)d_in[5];
    const float* bn1_m   = (const float*)d_in[6];
    const float* bn1_v   = (const float*)d_in[7];
    const float* gcn1_w  = (const float*)d_in[8];
    const float* gcn1_b  = (const float*)d_in[9];
    const float* gcn2_w  = (const float*)d_in[10];
    const float* gcn2_b  = (const float*)d_in[11];
    const float* conv2_w = (const float*)d_in[12];
    const float* bn2_g   = (const float*)d_in[13];
    const float* bn2_b   = (const float*)d_in[14];
    const float* bn2_m   = (const float*)d_in[15];
    const float* bn2_v   = (const float*)d_in[16];
    const float* conv3_w = (const float*)d_in[17];
    const float* bn3_g   = (const float*)d_in[18];
    const float* bn3_b   = (const float*)d_in[19];
    const float* bn3_m   = (const float*)d_in[20];
    const float* bn3_v   = (const float*)d_in[21];
    const float* dense_w = (const float*)d_in[22];
    const float* dense_b = (const float*)d_in[23];
    float* out = (float*)d_out;

    // Workspace layout (256B-aligned slots)
    char* ws = (char*)d_ws;
    size_t off = 0;
    auto alloc = [&](size_t bytes) { size_t o = off; off += (bytes + 255) & ~(size_t)255; return o; };
    size_t o_counters = alloc(2 * NN * sizeof(int));          // deg_i | cursor (zeroed)
    size_t o_rowstart = alloc((NN + 1) * sizeof(int));
    size_t o_csrsrc   = alloc(EE * sizeof(int));
    size_t o_csrnorm  = alloc(EE * sizeof(float));
    size_t o_dinv     = alloc(NN * sizeof(float));
    size_t o_h0       = alloc((size_t)NN * TT * K0C * sizeof(float));    // 16.8 MB
    size_t o_agg0     = alloc((size_t)NN * TT * K0C * sizeof(float));    // 16.8 MB
    size_t o_h1       = alloc((size_t)NN * TT * EMBC * sizeof(float));   // 67 MB
    size_t o_agg1     = alloc((size_t)NN * TT * EMBC * sizeof(float));   // 67 MB
    // Aliases (lifetimes disjoint): h2 -> h1 slot, h3 -> h0 slot, g1 -> agg0 slot
    size_t o_h2 = o_h1;
    size_t o_h3 = o_h0;
    size_t o_g1 = o_agg0;

    int*   deg_i    = (int*)(ws + o_counters);
    int*   cursor   = (int*)(ws + o_counters) + NN;
    int*   rowstart = (int*)(ws + o_rowstart);
    int*   csr_src  = (int*)(ws + o_csrsrc);
    float* csr_nrm  = (float*)(ws + o_csrnorm);
    float* dinv     = (float*)(ws + o_dinv);
    float* h0   = (float*)(ws + o_h0);
    float* agg0 = (float*)(ws + o_agg0);
    float* h1   = (float*)(ws + o_h1);
    float* agg1 = (float*)(ws + o_agg1);
    float* h2   = (float*)(ws + o_h2);
    float* h3   = (float*)(ws + o_h3);
    float* g1   = (float*)(ws + o_g1);

    hipMemsetAsync(deg_i, 0, 2 * NN * sizeof(int), stream);

    count_deg_kernel<<<EE / 256, 256, 0, stream>>>(ei, deg_i);
    dinv_kernel<<<NN / 256, 256, 0, stream>>>(deg_i, dinv);
    scan_kernel<<<1, 256, 0, stream>>>(deg_i, rowstart);
    fill_csr_kernel<<<EE / 256, 256, 0, stream>>>(ei, rowstart, cursor, dinv, csr_src, csr_nrm);

    conv1_bn_relu_kernel<<<(NN * TT * K0C) / 256, 256, 0, stream>>>(
        x, conv1_w, bn1_g, bn1_b, bn1_m, bn1_v, h0);

    aggregate_kernel<K0C><<<NN, 256, 0, stream>>>(h0, agg0, rowstart, csr_src, csr_nrm, dinv);
    gemm_bias_relu_kernel<K0C><<<(NN * TT) / 64, 256, 0, stream>>>(agg0, gcn1_w, gcn1_b, h1);

    aggregate_kernel<EMBC><<<NN, 256, 0, stream>>>(h1, agg1, rowstart, csr_src, csr_nrm, dinv);
    gemm_bias_relu_kernel<EMBC><<<(NN * TT) / 64, 256, 0, stream>>>(agg1, gcn2_w, gcn2_b, h2);

    conv2_fused_kernel<<<NN, 256, 0, stream>>>(h2, conv2_w, bn2_g, bn2_b, bn2_m, bn2_v, h3);
    graph_pool_kernel<<<BB, 256, 0, stream>>>(h3, g1);
    head_kernel<<<BB, 256, 0, stream>>>(g1, conv3_w, bn3_g, bn3_b, bn3_m, bn3_v,
                                        dense_w, dense_b, out);
}

// Round 2
// 405.071 us; speedup vs baseline: 1.4316x; 1.4316x over previous
//
#include <hip/hip_runtime.h>
#include <hip/hip_bf16.h>

// Problem constants (from reference)
#define NN 2048
#define TT 64
#define EE 16384
#define BB 64
#define K0C 32
#define EMBC 128
#define K1C 64
#define K2C 64
#define KSZ 7
#define POOLK 4
#define BNEPS 1e-5f

typedef __attribute__((ext_vector_type(8))) short short8;   // 8 bf16 (4 VGPRs)
typedef __attribute__((ext_vector_type(4))) float float4v;  // MFMA C/D frag

// float -> bf16 bits, round-to-nearest-even
static __device__ __forceinline__ unsigned short f2bf(float f) {
    unsigned int u = __float_as_uint(f);
    u += 0x7fffu + ((u >> 16) & 1u);
    return (unsigned short)(u >> 16);
}
static __device__ __forceinline__ float bflo(unsigned int u) { return __uint_as_float(u << 16); }
static __device__ __forceinline__ float bfhi(unsigned int u) { return __uint_as_float(u & 0xffff0000u); }

// ---------------------------------------------------------------------------
// Graph preprocessing
// ---------------------------------------------------------------------------
__global__ void count_deg_kernel(const int* __restrict__ ei, int* __restrict__ deg) {
    int e = blockIdx.x * 256 + threadIdx.x;
    if (e < EE) atomicAdd(&deg[ei[EE + e]], 1);   // dst = second row
}

__global__ void dinv_kernel(const int* __restrict__ deg, float* __restrict__ dinv) {
    int n = blockIdx.x * 256 + threadIdx.x;
    if (n < NN) dinv[n] = rsqrtf((float)deg[n] + 1.0f);   // +1 self loop
}

__global__ void scan_kernel(const int* __restrict__ deg, int* __restrict__ row_start) {
    __shared__ int tsum[256];
    int tid = threadIdx.x;
    int loc[8];
    int s = 0;
#pragma unroll
    for (int i = 0; i < 8; ++i) { loc[i] = s; s += deg[tid * 8 + i]; }
    tsum[tid] = s;
    __syncthreads();
    for (int off = 1; off < 256; off <<= 1) {
        int v = (tid >= off) ? tsum[tid - off] : 0;
        __syncthreads();
        tsum[tid] += v;
        __syncthreads();
    }
    int base = (tid > 0) ? tsum[tid - 1] : 0;
#pragma unroll
    for (int i = 0; i < 8; ++i) row_start[tid * 8 + i] = base + loc[i];
    if (tid == 255) row_start[NN] = tsum[255];
}

__global__ void fill_csr_kernel(const int* __restrict__ ei, const int* __restrict__ row_start,
                                int* __restrict__ cursor, const float* __restrict__ dinv,
                                int* __restrict__ csr_src, float* __restrict__ csr_norm) {
    int e = blockIdx.x * 256 + threadIdx.x;
    if (e >= EE) return;
    int s = ei[e];
    int d = ei[EE + e];
    int pos = row_start[d] + atomicAdd(&cursor[d], 1);
    csr_src[pos] = s;
    csr_norm[pos] = dinv[s] * dinv[d];
}

// ---------------------------------------------------------------------------
// Weight prep: transpose + cast to bf16.
//   Wt1[d][k] (128x32)  from gcn1_w (32,128)
//   Wt2[d][k] (128x128) from gcn2_w (128,128)
//   Bt [c][k] (64x896)  from conv2_w (7,128,64) with k = kk*128+cin
// ---------------------------------------------------------------------------
__global__ void prep_weights_kernel(const float* __restrict__ g1w, const float* __restrict__ g2w,
                                    const float* __restrict__ c2w,
                                    unsigned short* __restrict__ Wt1,
                                    unsigned short* __restrict__ Wt2,
                                    unsigned short* __restrict__ Bt) {
    int idx = blockIdx.x * 256 + threadIdx.x;
    if (idx < 4096) {
        int d = idx >> 5, k = idx & 31;
        Wt1[idx] = f2bf(g1w[k * 128 + d]);
    } else if (idx < 20480) {
        int j = idx - 4096;
        int d = j >> 7, k = j & 127;
        Wt2[j] = f2bf(g2w[k * 128 + d]);
    } else if (idx < 77824) {
        int j = idx - 20480;
        int c = j / 896, k = j % 896;
        Bt[j] = f2bf(c2w[k * 64 + c]);
    }
}

// ---------------------------------------------------------------------------
// conv1 (SAME, 1->32) + bn1 + relu : x (N,T) -> h0 bf16 (N,T,32)
// ---------------------------------------------------------------------------
__global__ void conv1_bn_relu_kernel(const float* __restrict__ x, const float* __restrict__ w,
                                     const float* __restrict__ g, const float* __restrict__ b,
                                     const float* __restrict__ m, const float* __restrict__ v,
                                     unsigned short* __restrict__ h0) {
    int idx = blockIdx.x * 256 + threadIdx.x;      // N*T*32 total
    int c = idx & 31;
    int t = (idx >> 5) & 63;
    int n = idx >> 11;
    float acc = 0.f;
#pragma unroll
    for (int k = 0; k < KSZ; ++k) {
        int tt = t + k - 3;
        if (tt >= 0 && tt < TT) acc += x[n * TT + tt] * w[k * K0C + c];
    }
    float scale = g[c] * rsqrtf(v[c] + BNEPS);
    float val = (acc - m[c]) * scale + b[c];
    h0[idx] = f2bf(fmaxf(val, 0.f));
}

// ---------------------------------------------------------------------------
// Aggregation (bf16 in/out, fp32 accumulate):
//   out[n] = dinv[n]^2 * h[n] + sum_e norm_e * h[src_e]
// h layout: (N, T*C) bf16 contiguous. One block per node, 256 threads.
// ---------------------------------------------------------------------------
template <int C>
__global__ __launch_bounds__(256) void aggregate_kernel(
        const unsigned short* __restrict__ h, unsigned short* __restrict__ out,
        const int* __restrict__ row_start, const int* __restrict__ csr_src,
        const float* __restrict__ csr_norm, const float* __restrict__ dinv) {
    constexpr int TC = TT * C;              // bf16 elements per node
    constexpr int V = TC / (8 * 256);       // uint4 (8 bf16) per thread: C=32 -> 1, C=128 -> 4
    __shared__ int s_src[256];
    __shared__ float s_w[256];
    int n = blockIdx.x;
    int tid = threadIdx.x;
    int rs = row_start[n], re = row_start[n + 1];
    float dn = dinv[n];
    float selfw = dn * dn;
    const uint4* hn = (const uint4*)(h + (size_t)n * TC);
    float acc[V][8];
#pragma unroll
    for (int vv = 0; vv < V; ++vv) {
        uint4 r = hn[tid + vv * 256];
        acc[vv][0] = selfw * bflo(r.x); acc[vv][1] = selfw * bfhi(r.x);
        acc[vv][2] = selfw * bflo(r.y); acc[vv][3] = selfw * bfhi(r.y);
        acc[vv][4] = selfw * bflo(r.z); acc[vv][5] = selfw * bfhi(r.z);
        acc[vv][6] = selfw * bflo(r.w); acc[vv][7] = selfw * bfhi(r.w);
    }
    for (int e0 = rs; e0 < re; e0 += 256) {
        int cnt = min(256, re - e0);
        if (tid < cnt) { s_src[tid] = csr_src[e0 + tid]; s_w[tid] = csr_norm[e0 + tid]; }
        __syncthreads();
        for (int j = 0; j < cnt; ++j) {
            const uint4* hs = (const uint4*)(h + (size_t)s_src[j] * TC);
            float wgt = s_w[j];
#pragma unroll
            for (int vv = 0; vv < V; ++vv) {
                uint4 r = hs[tid + vv * 256];
                acc[vv][0] += wgt * bflo(r.x); acc[vv][1] += wgt * bfhi(r.x);
                acc[vv][2] += wgt * bflo(r.y); acc[vv][3] += wgt * bfhi(r.y);
                acc[vv][4] += wgt * bflo(r.z); acc[vv][5] += wgt * bfhi(r.z);
                acc[vv][6] += wgt * bflo(r.w); acc[vv][7] += wgt * bfhi(r.w);
            }
        }
        __syncthreads();
    }
    uint4* o = (uint4*)(out + (size_t)n * TC);
#pragma unroll
    for (int vv = 0; vv < V; ++vv) {
        uint4 r;
        r.x = (unsigned int)f2bf(acc[vv][0]) | ((unsigned int)f2bf(acc[vv][1]) << 16);
        r.y = (unsigned int)f2bf(acc[vv][2]) | ((unsigned int)f2bf(acc[vv][3]) << 16);
        r.z = (unsigned int)f2bf(acc[vv][4]) | ((unsigned int)f2bf(acc[vv][5]) << 16);
        r.w = (unsigned int)f2bf(acc[vv][6]) | ((unsigned int)f2bf(acc[vv][7]) << 16);
        o[tid + vv * 256] = r;
    }
}

// ---------------------------------------------------------------------------
// MFMA GEMM: C(M,128) = relu(A(M,K) @ W(K,128) + bias), bf16 in/out, fp32 acc.
// Wt is pre-transposed (128, K). Block = 4 waves; wave = 16 rows x 128 cols
// (8 col-tiles of 16x16x32 MFMA). A-frag + B-frag are 16B contiguous loads.
// ---------------------------------------------------------------------------
template <int K>
__global__ __launch_bounds__(256) void gemm_mfma_kernel(
        const unsigned short* __restrict__ A, const unsigned short* __restrict__ Wt,
        const float* __restrict__ bias, unsigned short* __restrict__ C) {
    const int tid = threadIdx.x;
    const int wave = tid >> 6;
    const int lane = tid & 63;
    const int l15 = lane & 15;
    const int quad = lane >> 4;
    const size_t m0 = (size_t)blockIdx.x * 64 + wave * 16;

    float4v acc[8];
#pragma unroll
    for (int ct = 0; ct < 8; ++ct) acc[ct] = (float4v)0.f;

    const unsigned short* arow = A + (m0 + l15) * K;
#pragma unroll
    for (int kk = 0; kk < K / 32; ++kk) {
        short8 a = *(const short8*)(arow + kk * 32 + quad * 8);
#pragma unroll
        for (int ct = 0; ct < 8; ++ct) {
            short8 b = *(const short8*)(Wt + (size_t)(ct * 16 + l15) * K + kk * 32 + quad * 8);
            acc[ct] = __builtin_amdgcn_mfma_f32_16x16x32_bf16(a, b, acc[ct], 0, 0, 0);
        }
    }
    // C/D layout: col = lane&15, row = quad*4 + reg
#pragma unroll
    for (int ct = 0; ct < 8; ++ct) {
        int col = ct * 16 + l15;
        float bv = bias[col];
#pragma unroll
        for (int r = 0; r < 4; ++r) {
            size_t row = m0 + quad * 4 + r;
            C[row * 128 + col] = f2bf(fmaxf(acc[ct][r] + bv, 0.f));
        }
    }
}

// ---------------------------------------------------------------------------
// conv2 as implicit-im2col MFMA GEMM + bn2 + avgpool4 + relu, fused.
// A[t_out][k] = h2[n, t_out*128 + k] (contiguous window!), k in [0,896).
// Bt (64, 896) bf16. One block per node; wave w = output rows 16w..16w+15.
// Pool: each lane's 4 C-regs are rows quad*4+r -> exactly one pool group.
// ---------------------------------------------------------------------------
__global__ __launch_bounds__(256) void conv2_mfma_kernel(
        const unsigned short* __restrict__ h2, const unsigned short* __restrict__ Bt,
        const float* __restrict__ g2, const float* __restrict__ b2,
        const float* __restrict__ m2, const float* __restrict__ v2,
        float* __restrict__ h3) {
    const int n = blockIdx.x;
    const int tid = threadIdx.x;
    const int wave = tid >> 6;
    const int lane = tid & 63;
    const int l15 = lane & 15;
    const int quad = lane >> 4;
    const int trow = wave * 16 + l15;     // A row (t_out) this lane loads

    const unsigned short* arow = h2 + (size_t)n * (TT * EMBC) + trow * EMBC;
    float4v acc[4];
#pragma unroll
    for (int ct = 0; ct < 4; ++ct) acc[ct] = (float4v)0.f;

#pragma unroll
    for (int kk = 0; kk < 28; ++kk) {     // K = 896 = 28 * 32
        short8 a = *(const short8*)(arow + kk * 32 + quad * 8);
#pragma unroll
        for (int ct = 0; ct < 4; ++ct) {
            short8 b = *(const short8*)(Bt + (size_t)(ct * 16 + l15) * 896 + kk * 32 + quad * 8);
            acc[ct] = __builtin_amdgcn_mfma_f32_16x16x32_bf16(a, b, acc[ct], 0, 0, 0);
        }
    }
    int gidx = wave * 4 + quad;           // pool group (t_out rows 4g..4g+3)
    if (gidx < 14) {
#pragma unroll
        for (int ct = 0; ct < 4; ++ct) {
            int col = ct * 16 + l15;
            float p = 0.25f * (acc[ct][0] + acc[ct][1] + acc[ct][2] + acc[ct][3]);
            float scale = g2[col] * rsqrtf(v2[col] + BNEPS);
            float val = (p - m2[col]) * scale + b2[col];
            h3[((size_t)n * 14 + gidx) * K1C + col] = fmaxf(val, 0.f);
        }
    }
}

// ---------------------------------------------------------------------------
// Global mean pool per graph: h3 (N,14,64) -> g1 (B,14,64). batch = n/32.
// ---------------------------------------------------------------------------
__global__ void graph_pool_kernel(const float* __restrict__ h3, float* __restrict__ g1) {
    int b = blockIdx.x;
    for (int i = threadIdx.x; i < 14 * K1C; i += 256) {
        float acc = 0.f;
        for (int nn = 0; nn < 32; ++nn)
            acc += h3[((size_t)(b * 32 + nn)) * (14 * K1C) + i];
        g1[(size_t)b * (14 * K1C) + i] = acc * (1.f / 32.f);
    }
}

// ---------------------------------------------------------------------------
// Head: conv3 + bn3 + pool4 + relu + flatten + dense + log_softmax.
// ---------------------------------------------------------------------------
__global__ __launch_bounds__(256) void head_kernel(
        const float* __restrict__ g1, const float* __restrict__ w3,
        const float* __restrict__ g3, const float* __restrict__ b3,
        const float* __restrict__ m3, const float* __restrict__ v3,
        const float* __restrict__ dw, const float* __restrict__ db,
        float* __restrict__ out) {
    __shared__ float sg[14 * 64];
    __shared__ float sconv[8 * 64];
    __shared__ float sflat[128];
    __shared__ float slog[4];
    int b = blockIdx.x;
    int tid = threadIdx.x;
    for (int i = tid; i < 14 * 64; i += 256) sg[i] = g1[(size_t)b * (14 * 64) + i];
    __syncthreads();
    for (int i = tid; i < 8 * 64; i += 256) {
        int t = i >> 6, c = i & 63;
        float acc = 0.f;
        for (int k = 0; k < KSZ; ++k)
            for (int cin = 0; cin < 64; ++cin)
                acc += sg[(t + k) * 64 + cin] * w3[((size_t)(k * 64 + cin)) * 64 + c];
        sconv[i] = acc;
    }
    __syncthreads();
    for (int i = tid; i < 128; i += 256) {
        int j = i >> 6, c = i & 63;
        float p = 0.25f * (sconv[(4 * j + 0) * 64 + c] + sconv[(4 * j + 1) * 64 + c] +
                           sconv[(4 * j + 2) * 64 + c] + sconv[(4 * j + 3) * 64 + c]);
        float scale = g3[c] * rsqrtf(v3[c] + BNEPS);
        float val = (p - m3[c]) * scale + b3[c];
        sflat[i] = fmaxf(val, 0.f);
    }
    __syncthreads();
    if (tid < 4) {
        float acc = db[tid];
        for (int i = 0; i < 128; ++i) acc += sflat[i] * dw[i * 4 + tid];
        slog[tid] = acc;
    }
    __syncthreads();
    if (tid < 4) {
        float mx = fmaxf(fmaxf(slog[0], slog[1]), fmaxf(slog[2], slog[3]));
        float s = expf(slog[0] - mx) + expf(slog[1] - mx) +
                  expf(slog[2] - mx) + expf(slog[3] - mx);
        out[b * 4 + tid] = slog[tid] - mx - logf(s);
    }
}

// ---------------------------------------------------------------------------
extern "C" void kernel_launch(void* const* d_in, const int* in_sizes, int n_in,
                              void* d_out, int out_size, void* d_ws, size_t ws_size,
                              hipStream_t stream) {
    const float* x       = (const float*)d_in[0];
    const int*   ei      = (const int*)d_in[1];
    // d_in[2] = batch (arange//32, handled analytically)
    const float* conv1_w = (const float*)d_in[3];
    const float* bn1_g   = (const float*)d_in[4];
    const float* bn1_b   = (const float*)d_in[5];
    const float* bn1_m   = (const float*)d_in[6];
    const float* bn1_v   = (const float*)d_in[7];
    const float* gcn1_w  = (const float*)d_in[8];
    const float* gcn1_b  = (const float*)d_in[9];
    const float* gcn2_w  = (const float*)d_in[10];
    const float* gcn2_b  = (const float*)d_in[11];
    const float* conv2_w = (const float*)d_in[12];
    const float* bn2_g   = (const float*)d_in[13];
    const float* bn2_b   = (const float*)d_in[14];
    const float* bn2_m   = (const float*)d_in[15];
    const float* bn2_v   = (const float*)d_in[16];
    const float* conv3_w = (const float*)d_in[17];
    const float* bn3_g   = (const float*)d_in[18];
    const float* bn3_b   = (const float*)d_in[19];
    const float* bn3_m   = (const float*)d_in[20];
    const float* bn3_v   = (const float*)d_in[21];
    const float* dense_w = (const float*)d_in[22];
    const float* dense_b = (const float*)d_in[23];
    float* out = (float*)d_out;

    // Workspace layout (256B-aligned slots)
    char* ws = (char*)d_ws;
    size_t off = 0;
    auto alloc = [&](size_t bytes) { size_t o = off; off += (bytes + 255) & ~(size_t)255; return o; };
    size_t o_counters = alloc(2 * NN * sizeof(int));          // deg | cursor (zeroed)
    size_t o_rowstart = alloc((NN + 1) * sizeof(int));
    size_t o_csrsrc   = alloc(EE * sizeof(int));
    size_t o_csrnorm  = alloc(EE * sizeof(float));
    size_t o_dinv     = alloc(NN * sizeof(float));
    size_t o_wt1      = alloc(4096 * sizeof(unsigned short));
    size_t o_wt2      = alloc(16384 * sizeof(unsigned short));
    size_t o_bt       = alloc(57344 * sizeof(unsigned short));
    size_t o_h0       = alloc((size_t)NN * TT * K0C * sizeof(unsigned short));   // 8.4 MB
    size_t o_agg0     = alloc((size_t)NN * TT * K0C * sizeof(unsigned short));   // 8.4 MB
    size_t o_h1       = alloc((size_t)NN * TT * EMBC * sizeof(unsigned short));  // 33.5 MB
    size_t o_agg1     = alloc((size_t)NN * TT * EMBC * sizeof(unsigned short));  // 33.5 MB
    size_t o_h2       = alloc((size_t)NN * TT * EMBC * sizeof(unsigned short));  // 33.5 MB (+tail slack below)
    size_t o_h3       = alloc((size_t)NN * 14 * K1C * sizeof(float));            // 7.3 MB
    size_t o_g1       = alloc((size_t)BB * 14 * K1C * sizeof(float));
    (void)alloc(4096); // slack after g1 so conv2's discarded tail-row reads stay in-bounds

    int*   deg_i    = (int*)(ws + o_counters);
    int*   rowstart = (int*)(ws + o_rowstart);
    int*   csr_src  = (int*)(ws + o_csrsrc);
    float* csr_nrm  = (float*)(ws + o_csrnorm);
    float* dinv     = (float*)(ws + o_dinv);
    unsigned short* Wt1  = (unsigned short*)(ws + o_wt1);
    unsigned short* Wt2  = (unsigned short*)(ws + o_wt2);
    unsigned short* Bt   = (unsigned short*)(ws + o_bt);
    unsigned short* h0   = (unsigned short*)(ws + o_h0);
    unsigned short* agg0 = (unsigned short*)(ws + o_agg0);
    unsigned short* h1   = (unsigned short*)(ws + o_h1);
    unsigned short* agg1 = (unsigned short*)(ws + o_agg1);
    unsigned short* h2   = (unsigned short*)(ws + o_h2);
    float* h3 = (float*)(ws + o_h3);
    float* g1 = (float*)(ws + o_g1);
    int* cursor = deg_i + NN;

    hipMemsetAsync(deg_i, 0, 2 * NN * sizeof(int), stream);

    count_deg_kernel<<<EE / 256, 256, 0, stream>>>(ei, deg_i);
    dinv_kernel<<<NN / 256, 256, 0, stream>>>(deg_i, dinv);
    scan_kernel<<<1, 256, 0, stream>>>(deg_i, rowstart);
    fill_csr_kernel<<<EE / 256, 256, 0, stream>>>(ei, rowstart, cursor, dinv, csr_src, csr_nrm);
    prep_weights_kernel<<<304, 256, 0, stream>>>(gcn1_w, gcn2_w, conv2_w, Wt1, Wt2, Bt);

    conv1_bn_relu_kernel<<<(NN * TT * K0C) / 256, 256, 0, stream>>>(
        x, conv1_w, bn1_g, bn1_b, bn1_m, bn1_v, h0);

    aggregate_kernel<K0C><<<NN, 256, 0, stream>>>(h0, agg0, rowstart, csr_src, csr_nrm, dinv);
    gemm_mfma_kernel<K0C><<<NN, 256, 0, stream>>>(agg0, Wt1, gcn1_b, h1);

    aggregate_kernel<EMBC><<<NN, 256, 0, stream>>>(h1, agg1, rowstart, csr_src, csr_nrm, dinv);
    gemm_mfma_kernel<EMBC><<<NN, 256, 0, stream>>>(agg1, Wt2, gcn2_b, h2);

    conv2_mfma_kernel<<<NN, 256, 0, stream>>>(h2, Bt, bn2_g, bn2_b, bn2_m, bn2_v, h3);
    graph_pool_kernel<<<BB, 256, 0, stream>>>(h3, g1);
    head_kernel<<<BB, 256, 0, stream>>>(g1, conv3_w, bn3_g, bn3_b, bn3_m, bn3_v,
                                        dense_w, dense_b, out);
}

// Round 3
// 289.859 us; speedup vs baseline: 2.0007x; 1.3975x over previous
//
#include <hip/hip_runtime.h>
#include <hip/hip_bf16.h>

// Problem constants (from reference)
#define NN 2048
#define TT 64
#define EE 16384
#define BB 64
#define K0C 32
#define EMBC 128
#define K1C 64
#define K2C 64
#define KSZ 7
#define POOLK 4
#define BNEPS 1e-5f

typedef __attribute__((ext_vector_type(8))) short short8;     // 8 bf16 (4 VGPRs)
typedef __attribute__((ext_vector_type(16))) float floatx16;  // 32x32 MFMA C/D frag

// float -> bf16 bits, round-to-nearest-even
static __device__ __forceinline__ unsigned short f2bf(float f) {
    unsigned int u = __float_as_uint(f);
    u += 0x7fffu + ((u >> 16) & 1u);
    return (unsigned short)(u >> 16);
}
static __device__ __forceinline__ float bflo(unsigned int u) { return __uint_as_float(u << 16); }
static __device__ __forceinline__ float bfhi(unsigned int u) { return __uint_as_float(u & 0xffff0000u); }

// ---------------------------------------------------------------------------
// Graph preprocessing
// ---------------------------------------------------------------------------
__global__ void count_deg_kernel(const int* __restrict__ ei, int* __restrict__ deg) {
    int e = blockIdx.x * 256 + threadIdx.x;
    if (e < EE) atomicAdd(&deg[ei[EE + e]], 1);   // dst = second row
}

__global__ void dinv_kernel(const int* __restrict__ deg, float* __restrict__ dinv) {
    int n = blockIdx.x * 256 + threadIdx.x;
    if (n < NN) dinv[n] = rsqrtf((float)deg[n] + 1.0f);   // +1 self loop
}

__global__ void scan_kernel(const int* __restrict__ deg, int* __restrict__ row_start) {
    __shared__ int tsum[256];
    int tid = threadIdx.x;
    int loc[8];
    int s = 0;
#pragma unroll
    for (int i = 0; i < 8; ++i) { loc[i] = s; s += deg[tid * 8 + i]; }
    tsum[tid] = s;
    __syncthreads();
    for (int off = 1; off < 256; off <<= 1) {
        int v = (tid >= off) ? tsum[tid - off] : 0;
        __syncthreads();
        tsum[tid] += v;
        __syncthreads();
    }
    int base = (tid > 0) ? tsum[tid - 1] : 0;
#pragma unroll
    for (int i = 0; i < 8; ++i) row_start[tid * 8 + i] = base + loc[i];
    if (tid == 255) row_start[NN] = tsum[255];
}

__global__ void fill_csr_kernel(const int* __restrict__ ei, const int* __restrict__ row_start,
                                int* __restrict__ cursor, const float* __restrict__ dinv,
                                int* __restrict__ csr_src, float* __restrict__ csr_norm) {
    int e = blockIdx.x * 256 + threadIdx.x;
    if (e >= EE) return;
    int s = ei[e];
    int d = ei[EE + e];
    int pos = row_start[d] + atomicAdd(&cursor[d], 1);
    csr_src[pos] = s;
    csr_norm[pos] = dinv[s] * dinv[d];
}

// ---------------------------------------------------------------------------
// Weight prep: transpose + cast to bf16.
//   Wt1[d][k] (128x32)  from gcn1_w (32,128)
//   Wt2[d][k] (128x128) from gcn2_w (128,128)
//   Bt [c][k] (64x896)  from conv2_w (7,128,64) with k = kw*128+cin
// ---------------------------------------------------------------------------
__global__ void prep_weights_kernel(const float* __restrict__ g1w, const float* __restrict__ g2w,
                                    const float* __restrict__ c2w,
                                    unsigned short* __restrict__ Wt1,
                                    unsigned short* __restrict__ Wt2,
                                    unsigned short* __restrict__ Bt) {
    int idx = blockIdx.x * 256 + threadIdx.x;
    if (idx < 4096) {
        int d = idx >> 5, k = idx & 31;
        Wt1[idx] = f2bf(g1w[k * 128 + d]);
    } else if (idx < 20480) {
        int j = idx - 4096;
        int d = j >> 7, k = j & 127;
        Wt2[j] = f2bf(g2w[k * 128 + d]);
    } else if (idx < 77824) {
        int j = idx - 20480;
        int c = j / 896, k = j % 896;
        Bt[j] = f2bf(c2w[k * 64 + c]);
    }
}

// ---------------------------------------------------------------------------
// conv1 (SAME, 1->32) + bn1 + relu : x (N,T) -> h0 bf16 (N,T,32)
// ---------------------------------------------------------------------------
__global__ void conv1_bn_relu_kernel(const float* __restrict__ x, const float* __restrict__ w,
                                     const float* __restrict__ g, const float* __restrict__ b,
                                     const float* __restrict__ m, const float* __restrict__ v,
                                     unsigned short* __restrict__ h0) {
    int idx = blockIdx.x * 256 + threadIdx.x;      // N*T*32 total
    int c = idx & 31;
    int t = (idx >> 5) & 63;
    int n = idx >> 11;
    float acc = 0.f;
#pragma unroll
    for (int k = 0; k < KSZ; ++k) {
        int tt = t + k - 3;
        if (tt >= 0 && tt < TT) acc += x[n * TT + tt] * w[k * K0C + c];
    }
    float scale = g[c] * rsqrtf(v[c] + BNEPS);
    float val = (acc - m[c]) * scale + b[c];
    h0[idx] = f2bf(fmaxf(val, 0.f));
}

// ---------------------------------------------------------------------------
// Fused GCN layer: aggregate (gather, fp32 acc) -> LDS (bf16, padded) ->
// 32x32x16 MFMA GEMM with Wt (128,C) -> relu(+bias) -> out bf16 (N,T,128).
// One block per node, 256 threads / 4 waves. Wave = (rowhalf, colhalf):
// 32 rows x 64 cols (2 col-tiles of 32).
// ---------------------------------------------------------------------------
template <int C>
__global__ __launch_bounds__(256) void gcn_fused_kernel(
        const unsigned short* __restrict__ h, const unsigned short* __restrict__ Wt,
        const float* __restrict__ bias, unsigned short* __restrict__ out,
        const int* __restrict__ row_start, const int* __restrict__ csr_src,
        const float* __restrict__ csr_norm, const float* __restrict__ dinv) {
    constexpr int TC = TT * C;            // bf16 elems per node
    constexpr int V = TC / (8 * 256);     // uint4 per thread (C=32 -> 1, C=128 -> 4)
    constexpr int STRIDE = C + 8;         // padded LDS row stride (elems)
    __shared__ __align__(16) unsigned short sA[TT * STRIDE];
    __shared__ int s_src[256];
    __shared__ float s_w[256];

    const int n = blockIdx.x;
    const int tid = threadIdx.x;

    // ---- phase 1: gather-aggregate into registers ----
    int rs = row_start[n], re = row_start[n + 1];
    float dn = dinv[n];
    float selfw = dn * dn;
    const uint4* hn = (const uint4*)(h + (size_t)n * TC);
    float acc[V][8];
#pragma unroll
    for (int vv = 0; vv < V; ++vv) {
        uint4 r = hn[tid + vv * 256];
        acc[vv][0] = selfw * bflo(r.x); acc[vv][1] = selfw * bfhi(r.x);
        acc[vv][2] = selfw * bflo(r.y); acc[vv][3] = selfw * bfhi(r.y);
        acc[vv][4] = selfw * bflo(r.z); acc[vv][5] = selfw * bfhi(r.z);
        acc[vv][6] = selfw * bflo(r.w); acc[vv][7] = selfw * bfhi(r.w);
    }
    for (int e0 = rs; e0 < re; e0 += 256) {
        int cnt = min(256, re - e0);
        if (tid < cnt) { s_src[tid] = csr_src[e0 + tid]; s_w[tid] = csr_norm[e0 + tid]; }
        __syncthreads();
        for (int j = 0; j < cnt; ++j) {
            const uint4* hs = (const uint4*)(h + (size_t)s_src[j] * TC);
            float wgt = s_w[j];
#pragma unroll
            for (int vv = 0; vv < V; ++vv) {
                uint4 r = hs[tid + vv * 256];
                acc[vv][0] += wgt * bflo(r.x); acc[vv][1] += wgt * bfhi(r.x);
                acc[vv][2] += wgt * bflo(r.y); acc[vv][3] += wgt * bfhi(r.y);
                acc[vv][4] += wgt * bflo(r.z); acc[vv][5] += wgt * bfhi(r.z);
                acc[vv][6] += wgt * bflo(r.w); acc[vv][7] += wgt * bfhi(r.w);
            }
        }
        __syncthreads();
    }
    // ---- write aggregated tile to padded LDS (bf16) ----
#pragma unroll
    for (int vv = 0; vv < V; ++vv) {
        int f0 = (tid + vv * 256) * 8;
        int row = f0 / C, col = f0 % C;
        uint4 r;
        r.x = (unsigned int)f2bf(acc[vv][0]) | ((unsigned int)f2bf(acc[vv][1]) << 16);
        r.y = (unsigned int)f2bf(acc[vv][2]) | ((unsigned int)f2bf(acc[vv][3]) << 16);
        r.z = (unsigned int)f2bf(acc[vv][4]) | ((unsigned int)f2bf(acc[vv][5]) << 16);
        r.w = (unsigned int)f2bf(acc[vv][6]) | ((unsigned int)f2bf(acc[vv][7]) << 16);
        *(uint4*)&sA[row * STRIDE + col] = r;
    }
    __syncthreads();

    // ---- phase 2: 32x32x16 MFMA GEMM, out = relu(agg @ W + bias) ----
    const int wave = tid >> 6;
    const int lane = tid & 63;
    const int l31 = lane & 31;
    const int q = lane >> 5;
    const int rh = wave & 1;
    const int ch = wave >> 1;

    floatx16 accv[2];
    accv[0] = (floatx16)0.f;
    accv[1] = (floatx16)0.f;
#pragma unroll
    for (int kk = 0; kk < C / 16; ++kk) {
        short8 a = *(const short8*)&sA[(32 * rh + l31) * STRIDE + kk * 16 + q * 8];
#pragma unroll
        for (int ct = 0; ct < 2; ++ct) {
            short8 b = *(const short8*)(Wt + (size_t)(64 * ch + 32 * ct + l31) * C + kk * 16 + q * 8);
            accv[ct] = __builtin_amdgcn_mfma_f32_32x32x16_bf16(a, b, accv[ct], 0, 0, 0);
        }
    }
    // C/D layout (32x32): col = lane&31, row = (reg&3) + 8*(reg>>2) + 4*(lane>>5)
    unsigned short* orow = out + (size_t)n * (TT * 128);
#pragma unroll
    for (int ct = 0; ct < 2; ++ct) {
        int col = 64 * ch + 32 * ct + l31;
        float bv = bias[col];
#pragma unroll
        for (int r = 0; r < 16; ++r) {
            int row = (r & 3) + 8 * (r >> 2) + 4 * q + 32 * rh;
            orow[row * 128 + col] = f2bf(fmaxf(accv[ct][r] + bv, 0.f));
        }
    }
}

// ---------------------------------------------------------------------------
// conv2 as implicit-im2col 32x32x16 MFMA GEMM + bn2 + avgpool4 + relu, fused.
// One block per node; h2 node row (64x128) staged in padded LDS (+6 guard
// rows for im2col tail reads, zero-filled). Wave = (rowhalf, colhalf):
// 32 t_out rows x 32 cols. Pool groups fall out of the C/D row layout.
// ---------------------------------------------------------------------------
__global__ __launch_bounds__(256) void conv2_mfma_kernel(
        const unsigned short* __restrict__ h2, const unsigned short* __restrict__ Bt,
        const float* __restrict__ g2, const float* __restrict__ b2,
        const float* __restrict__ m2, const float* __restrict__ v2,
        float* __restrict__ h3) {
    constexpr int STRIDE = 136;
    __shared__ __align__(16) unsigned short sA[70 * STRIDE];
    const int n = blockIdx.x;
    const int tid = threadIdx.x;

    const uint4* src = (const uint4*)(h2 + (size_t)n * (TT * EMBC));
#pragma unroll
    for (int it = 0; it < 4; ++it) {
        int idx = tid + it * 256;       // 8-elem chunk index
        int f0 = idx * 8;
        int row = f0 >> 7, col = f0 & 127;
        *(uint4*)&sA[row * STRIDE + col] = src[idx];
    }
    // zero guard rows 64..69 (6*136 = 816 elems = 102 uint4)
    for (int i = tid; i < 102; i += 256) {
        uint4 z; z.x = z.y = z.z = z.w = 0u;
        *(uint4*)&sA[64 * STRIDE + i * 8] = z;
    }
    __syncthreads();

    const int wave = tid >> 6;
    const int lane = tid & 63;
    const int l31 = lane & 31;
    const int q = lane >> 5;
    const int rh = wave & 1;
    const int ch = wave >> 1;

    floatx16 acc = (floatx16)0.f;
#pragma unroll
    for (int kk = 0; kk < 56; ++kk) {   // K = 896 = 56 * 16
        int flat = (32 * rh + l31) * 128 + kk * 16 + q * 8;  // im2col: contiguous window
        short8 a = *(const short8*)&sA[(flat >> 7) * STRIDE + (flat & 127)];
        short8 b = *(const short8*)(Bt + (size_t)(32 * ch + l31) * 896 + kk * 16 + q * 8);
        acc = __builtin_amdgcn_mfma_f32_32x32x16_bf16(a, b, acc, 0, 0, 0);
    }
    // regs 4j..4j+3 = rows (8j + 4q + 32rh) + {0..3} = pool group 2j + q + 8rh
    int col = 32 * ch + l31;
    float scale = g2[col] * rsqrtf(v2[col] + BNEPS);
    float mean = m2[col], beta = b2[col];
#pragma unroll
    for (int j = 0; j < 4; ++j) {
        int grp = 2 * j + q + 8 * rh;
        if (grp < 14) {
            float p = 0.25f * (acc[4 * j] + acc[4 * j + 1] + acc[4 * j + 2] + acc[4 * j + 3]);
            float val = (p - mean) * scale + beta;
            h3[((size_t)n * 14 + grp) * K1C + col] = fmaxf(val, 0.f);
        }
    }
}

// ---------------------------------------------------------------------------
// Global mean pool per graph: h3 (N,14,64) -> g1 (B,14,64). batch = n/32.
// ---------------------------------------------------------------------------
__global__ void graph_pool_kernel(const float* __restrict__ h3, float* __restrict__ g1) {
    int b = blockIdx.x;
    for (int i = threadIdx.x; i < 14 * K1C; i += 256) {
        float acc = 0.f;
        for (int nn = 0; nn < 32; ++nn)
            acc += h3[((size_t)(b * 32 + nn)) * (14 * K1C) + i];
        g1[(size_t)b * (14 * K1C) + i] = acc * (1.f / 32.f);
    }
}

// ---------------------------------------------------------------------------
// Head: conv3 + bn3 + pool4 + relu + flatten + dense + log_softmax.
// ---------------------------------------------------------------------------
__global__ __launch_bounds__(256) void head_kernel(
        const float* __restrict__ g1, const float* __restrict__ w3,
        const float* __restrict__ g3, const float* __restrict__ b3,
        const float* __restrict__ m3, const float* __restrict__ v3,
        const float* __restrict__ dw, const float* __restrict__ db,
        float* __restrict__ out) {
    __shared__ float sg[14 * 64];
    __shared__ float sconv[8 * 64];
    __shared__ float sflat[128];
    __shared__ float slog[4];
    int b = blockIdx.x;
    int tid = threadIdx.x;
    for (int i = tid; i < 14 * 64; i += 256) sg[i] = g1[(size_t)b * (14 * 64) + i];
    __syncthreads();
    for (int i = tid; i < 8 * 64; i += 256) {
        int t = i >> 6, c = i & 63;
        float acc = 0.f;
        for (int k = 0; k < KSZ; ++k)
            for (int cin = 0; cin < 64; ++cin)
                acc += sg[(t + k) * 64 + cin] * w3[((size_t)(k * 64 + cin)) * 64 + c];
        sconv[i] = acc;
    }
    __syncthreads();
    for (int i = tid; i < 128; i += 256) {
        int j = i >> 6, c = i & 63;
        float p = 0.25f * (sconv[(4 * j + 0) * 64 + c] + sconv[(4 * j + 1) * 64 + c] +
                           sconv[(4 * j + 2) * 64 + c] + sconv[(4 * j + 3) * 64 + c]);
        float scale = g3[c] * rsqrtf(v3[c] + BNEPS);
        float val = (p - m3[c]) * scale + b3[c];
        sflat[i] = fmaxf(val, 0.f);
    }
    __syncthreads();
    if (tid < 4) {
        float acc = db[tid];
        for (int i = 0; i < 128; ++i) acc += sflat[i] * dw[i * 4 + tid];
        slog[tid] = acc;
    }
    __syncthreads();
    if (tid < 4) {
        float mx = fmaxf(fmaxf(slog[0], slog[1]), fmaxf(slog[2], slog[3]));
        float s = expf(slog[0] - mx) + expf(slog[1] - mx) +
                  expf(slog[2] - mx) + expf(slog[3] - mx);
        out[b * 4 + tid] = slog[tid] - mx - logf(s);
    }
}

// ---------------------------------------------------------------------------
extern "C" void kernel_launch(void* const* d_in, const int* in_sizes, int n_in,
                              void* d_out, int out_size, void* d_ws, size_t ws_size,
                              hipStream_t stream) {
    const float* x       = (const float*)d_in[0];
    const int*   ei      = (const int*)d_in[1];
    // d_in[2] = batch (arange//32, handled analytically)
    const float* conv1_w = (const float*)d_in[3];
    const float* bn1_g   = (const float*)d_in[4];
    const float* bn1_b   = (const float*)d_in[5];
    const float* bn1_m   = (const float*)d_in[6];
    const float* bn1_v   = (const float*)d_in[7];
    const float* gcn1_w  = (const float*)d_in[8];
    const float* gcn1_b  = (const float*)d_in[9];
    const float* gcn2_w  = (const float*)d_in[10];
    const float* gcn2_b  = (const float*)d_in[11];
    const float* conv2_w = (const float*)d_in[12];
    const float* bn2_g   = (const float*)d_in[13];
    const float* bn2_b   = (const float*)d_in[14];
    const float* bn2_m   = (const float*)d_in[15];
    const float* bn2_v   = (const float*)d_in[16];
    const float* conv3_w = (const float*)d_in[17];
    const float* bn3_g   = (const float*)d_in[18];
    const float* bn3_b   = (const float*)d_in[19];
    const float* bn3_m   = (const float*)d_in[20];
    const float* bn3_v   = (const float*)d_in[21];
    const float* dense_w = (const float*)d_in[22];
    const float* dense_b = (const float*)d_in[23];
    float* out = (float*)d_out;

    // Workspace layout (256B-aligned slots)
    char* ws = (char*)d_ws;
    size_t off = 0;
    auto alloc = [&](size_t bytes) { size_t o = off; off += (bytes + 255) & ~(size_t)255; return o; };
    size_t o_counters = alloc(2 * NN * sizeof(int));          // deg | cursor (zeroed)
    size_t o_rowstart = alloc((NN + 1) * sizeof(int));
    size_t o_csrsrc   = alloc(EE * sizeof(int));
    size_t o_csrnorm  = alloc(EE * sizeof(float));
    size_t o_dinv     = alloc(NN * sizeof(float));
    size_t o_wt1      = alloc(4096 * sizeof(unsigned short));
    size_t o_wt2      = alloc(16384 * sizeof(unsigned short));
    size_t o_bt       = alloc(57344 * sizeof(unsigned short));
    size_t o_h0       = alloc((size_t)NN * TT * K0C * sizeof(unsigned short));   // 8.4 MB
    size_t o_h1       = alloc((size_t)NN * TT * EMBC * sizeof(unsigned short));  // 33.5 MB
    size_t o_h2       = alloc((size_t)NN * TT * EMBC * sizeof(unsigned short));  // 33.5 MB
    size_t o_h3       = alloc((size_t)NN * 14 * K1C * sizeof(float));            // 7.3 MB
    size_t o_g1       = alloc((size_t)BB * 14 * K1C * sizeof(float));
    (void)alloc(4096); // slack

    int*   deg_i    = (int*)(ws + o_counters);
    int*   rowstart = (int*)(ws + o_rowstart);
    int*   csr_src  = (int*)(ws + o_csrsrc);
    float* csr_nrm  = (float*)(ws + o_csrnorm);
    float* dinv     = (float*)(ws + o_dinv);
    unsigned short* Wt1 = (unsigned short*)(ws + o_wt1);
    unsigned short* Wt2 = (unsigned short*)(ws + o_wt2);
    unsigned short* Bt  = (unsigned short*)(ws + o_bt);
    unsigned short* h0  = (unsigned short*)(ws + o_h0);
    unsigned short* h1  = (unsigned short*)(ws + o_h1);
    unsigned short* h2  = (unsigned short*)(ws + o_h2);
    float* h3 = (float*)(ws + o_h3);
    float* g1 = (float*)(ws + o_g1);
    int* cursor = deg_i + NN;

    hipMemsetAsync(deg_i, 0, 2 * NN * sizeof(int), stream);

    count_deg_kernel<<<EE / 256, 256, 0, stream>>>(ei, deg_i);
    dinv_kernel<<<NN / 256, 256, 0, stream>>>(deg_i, dinv);
    scan_kernel<<<1, 256, 0, stream>>>(deg_i, rowstart);
    fill_csr_kernel<<<EE / 256, 256, 0, stream>>>(ei, rowstart, cursor, dinv, csr_src, csr_nrm);
    prep_weights_kernel<<<304, 256, 0, stream>>>(gcn1_w, gcn2_w, conv2_w, Wt1, Wt2, Bt);

    conv1_bn_relu_kernel<<<(NN * TT * K0C) / 256, 256, 0, stream>>>(
        x, conv1_w, bn1_g, bn1_b, bn1_m, bn1_v, h0);

    gcn_fused_kernel<K0C><<<NN, 256, 0, stream>>>(h0, Wt1, gcn1_b, h1,
                                                  rowstart, csr_src, csr_nrm, dinv);
    gcn_fused_kernel<EMBC><<<NN, 256, 0, stream>>>(h1, Wt2, gcn2_b, h2,
                                                   rowstart, csr_src, csr_nrm, dinv);

    conv2_mfma_kernel<<<NN, 256, 0, stream>>>(h2, Bt, bn2_g, bn2_b, bn2_m, bn2_v, h3);
    graph_pool_kernel<<<BB, 256, 0, stream>>>(h3, g1);
    head_kernel<<<BB, 256, 0, stream>>>(g1, conv3_w, bn3_g, bn3_b, bn3_m, bn3_v,
                                        dense_w, dense_b, out);
}

// Round 4
// 283.307 us; speedup vs baseline: 2.0470x; 1.0231x over previous
//
#include <hip/hip_runtime.h>
#include <hip/hip_bf16.h>

// Problem constants (from reference)
#define NN 2048
#define TT 64
#define EE 16384
#define BB 64
#define K0C 32
#define EMBC 128
#define K1C 64
#define K2C 64
#define KSZ 7
#define POOLK 4
#define BNEPS 1e-5f

typedef __attribute__((ext_vector_type(8))) short short8;     // 8 bf16 (4 VGPRs)
typedef __attribute__((ext_vector_type(16))) float floatx16;  // 32x32 MFMA C/D frag

// float -> bf16 bits, round-to-nearest-even
static __device__ __forceinline__ unsigned short f2bf(float f) {
    unsigned int u = __float_as_uint(f);
    u += 0x7fffu + ((u >> 16) & 1u);
    return (unsigned short)(u >> 16);
}
static __device__ __forceinline__ float bflo(unsigned int u) { return __uint_as_float(u << 16); }
static __device__ __forceinline__ float bfhi(unsigned int u) { return __uint_as_float(u & 0xffff0000u); }

// ---------------------------------------------------------------------------
// Graph preprocessing
// ---------------------------------------------------------------------------
__global__ void count_deg_kernel(const int* __restrict__ ei, int* __restrict__ deg) {
    int e = blockIdx.x * 256 + threadIdx.x;
    if (e < EE) atomicAdd(&deg[ei[EE + e]], 1);   // dst = second row
}

__global__ void dinv_kernel(const int* __restrict__ deg, float* __restrict__ dinv) {
    int n = blockIdx.x * 256 + threadIdx.x;
    if (n < NN) dinv[n] = rsqrtf((float)deg[n] + 1.0f);   // +1 self loop
}

__global__ void scan_kernel(const int* __restrict__ deg, int* __restrict__ row_start) {
    __shared__ int tsum[256];
    int tid = threadIdx.x;
    int loc[8];
    int s = 0;
#pragma unroll
    for (int i = 0; i < 8; ++i) { loc[i] = s; s += deg[tid * 8 + i]; }
    tsum[tid] = s;
    __syncthreads();
    for (int off = 1; off < 256; off <<= 1) {
        int v = (tid >= off) ? tsum[tid - off] : 0;
        __syncthreads();
        tsum[tid] += v;
        __syncthreads();
    }
    int base = (tid > 0) ? tsum[tid - 1] : 0;
#pragma unroll
    for (int i = 0; i < 8; ++i) row_start[tid * 8 + i] = base + loc[i];
    if (tid == 255) row_start[NN] = tsum[255];
}

__global__ void fill_csr_kernel(const int* __restrict__ ei, const int* __restrict__ row_start,
                                int* __restrict__ cursor, const float* __restrict__ dinv,
                                int* __restrict__ csr_src, float* __restrict__ csr_norm) {
    int e = blockIdx.x * 256 + threadIdx.x;
    if (e >= EE) return;
    int s = ei[e];
    int d = ei[EE + e];
    int pos = row_start[d] + atomicAdd(&cursor[d], 1);
    csr_src[pos] = s;
    csr_norm[pos] = dinv[s] * dinv[d];
}

// ---------------------------------------------------------------------------
// Weight prep: transpose + cast to bf16.
//   Wt1[d][k] (128x32)  from gcn1_w (32,128)
//   Wt2[d][k] (128x128) from gcn2_w (128,128)
//   Bt [c][k] (64x896)  from conv2_w (7,128,64) with k = kw*128+cin
// ---------------------------------------------------------------------------
__global__ void prep_weights_kernel(const float* __restrict__ g1w, const float* __restrict__ g2w,
                                    const float* __restrict__ c2w,
                                    unsigned short* __restrict__ Wt1,
                                    unsigned short* __restrict__ Wt2,
                                    unsigned short* __restrict__ Bt) {
    int idx = blockIdx.x * 256 + threadIdx.x;
    if (idx < 4096) {
        int d = idx >> 5, k = idx & 31;
        Wt1[idx] = f2bf(g1w[k * 128 + d]);
    } else if (idx < 20480) {
        int j = idx - 4096;
        int d = j >> 7, k = j & 127;
        Wt2[j] = f2bf(g2w[k * 128 + d]);
    } else if (idx < 77824) {
        int j = idx - 20480;
        int c = j / 896, k = j % 896;
        Bt[j] = f2bf(c2w[k * 64 + c]);
    }
}

// ---------------------------------------------------------------------------
// conv1 (SAME, 1->32) + bn1 + relu : x (N,T) -> h0 bf16 (N,T,32)
// ---------------------------------------------------------------------------
__global__ void conv1_bn_relu_kernel(const float* __restrict__ x, const float* __restrict__ w,
                                     const float* __restrict__ g, const float* __restrict__ b,
                                     const float* __restrict__ m, const float* __restrict__ v,
                                     unsigned short* __restrict__ h0) {
    int idx = blockIdx.x * 256 + threadIdx.x;      // N*T*32 total
    int c = idx & 31;
    int t = (idx >> 5) & 63;
    int n = idx >> 11;
    float acc = 0.f;
#pragma unroll
    for (int k = 0; k < KSZ; ++k) {
        int tt = t + k - 3;
        if (tt >= 0 && tt < TT) acc += x[n * TT + tt] * w[k * K0C + c];
    }
    float scale = g[c] * rsqrtf(v[c] + BNEPS);
    float val = (acc - m[c]) * scale + b[c];
    h0[idx] = f2bf(fmaxf(val, 0.f));
}

// ---------------------------------------------------------------------------
// GCN layer 1 fused (C=32): pipelined gather-aggregate -> LDS -> 32x32x16
// MFMA (K=32) -> relu(+bias) -> h1 bf16 (N,T,128). One block per node.
// ---------------------------------------------------------------------------
__global__ __launch_bounds__(256) void gcn1_fused_kernel(
        const unsigned short* __restrict__ h, const unsigned short* __restrict__ Wt,
        const float* __restrict__ bias, unsigned short* __restrict__ out,
        const int* __restrict__ row_start, const int* __restrict__ csr_src,
        const float* __restrict__ csr_norm, const float* __restrict__ dinv) {
    constexpr int TC = TT * K0C;          // 2048 elems per node
    constexpr int STRIDE = K0C + 8;       // 40
    __shared__ __align__(16) unsigned short sA[TT * STRIDE];
    __shared__ int s_src[256];
    __shared__ float s_w[256];

    const int n = blockIdx.x;
    const int tid = threadIdx.x;

    int rs = row_start[n], re = row_start[n + 1];
    float dn = dinv[n];
    float selfw = dn * dn;
    const uint4* hn = (const uint4*)(h + (size_t)n * TC);
    float acc[8];
    {
        uint4 r = hn[tid];
        acc[0] = selfw * bflo(r.x); acc[1] = selfw * bfhi(r.x);
        acc[2] = selfw * bflo(r.y); acc[3] = selfw * bfhi(r.y);
        acc[4] = selfw * bflo(r.z); acc[5] = selfw * bfhi(r.z);
        acc[6] = selfw * bflo(r.w); acc[7] = selfw * bfhi(r.w);
    }
    for (int e0 = rs; e0 < re; e0 += 256) {
        int cnt = min(256, re - e0);
        if (tid < cnt) { s_src[tid] = csr_src[e0 + tid]; s_w[tid] = csr_norm[e0 + tid]; }
        __syncthreads();
        // 2-deep pipelined edge loop
        uint4 p0, p1;
        if (cnt > 0) p0 = ((const uint4*)(h + (size_t)s_src[0] * TC))[tid];
        if (cnt > 1) p1 = ((const uint4*)(h + (size_t)s_src[1] * TC))[tid];
        for (int j = 0; j < cnt; ++j) {
            uint4 r = (j & 1) ? p1 : p0;
            float wgt = s_w[j];
            if (j + 2 < cnt) {
                uint4 np = ((const uint4*)(h + (size_t)s_src[j + 2] * TC))[tid];
                if (j & 1) p1 = np; else p0 = np;
            }
            acc[0] += wgt * bflo(r.x); acc[1] += wgt * bfhi(r.x);
            acc[2] += wgt * bflo(r.y); acc[3] += wgt * bfhi(r.y);
            acc[4] += wgt * bflo(r.z); acc[5] += wgt * bfhi(r.z);
            acc[6] += wgt * bflo(r.w); acc[7] += wgt * bfhi(r.w);
        }
        __syncthreads();
    }
    // write aggregated tile to padded LDS
    {
        int f0 = tid * 8;
        int row = f0 >> 5, col = f0 & 31;
        uint4 r;
        r.x = (unsigned int)f2bf(acc[0]) | ((unsigned int)f2bf(acc[1]) << 16);
        r.y = (unsigned int)f2bf(acc[2]) | ((unsigned int)f2bf(acc[3]) << 16);
        r.z = (unsigned int)f2bf(acc[4]) | ((unsigned int)f2bf(acc[5]) << 16);
        r.w = (unsigned int)f2bf(acc[6]) | ((unsigned int)f2bf(acc[7]) << 16);
        *(uint4*)&sA[row * STRIDE + col] = r;
    }
    __syncthreads();

    // MFMA: (64x32) @ (32x128) -> 64x128
    const int wave = tid >> 6;
    const int lane = tid & 63;
    const int l31 = lane & 31;
    const int q = lane >> 5;
    const int rh = wave & 1;
    const int ch = wave >> 1;

    floatx16 accv[2];
    accv[0] = (floatx16)0.f;
    accv[1] = (floatx16)0.f;
#pragma unroll
    for (int kk = 0; kk < 2; ++kk) {
        short8 a = *(const short8*)&sA[(32 * rh + l31) * STRIDE + kk * 16 + q * 8];
#pragma unroll
        for (int ct = 0; ct < 2; ++ct) {
            short8 b = *(const short8*)(Wt + (size_t)(64 * ch + 32 * ct + l31) * K0C + kk * 16 + q * 8);
            accv[ct] = __builtin_amdgcn_mfma_f32_32x32x16_bf16(a, b, accv[ct], 0, 0, 0);
        }
    }
    unsigned short* orow = out + (size_t)n * (TT * 128);
#pragma unroll
    for (int ct = 0; ct < 2; ++ct) {
        int col = 64 * ch + 32 * ct + l31;
        float bv = bias[col];
#pragma unroll
        for (int r = 0; r < 16; ++r) {
            int row = (r & 3) + 8 * (r >> 2) + 4 * q + 32 * rh;
            orow[row * 128 + col] = f2bf(fmaxf(accv[ct][r] + bv, 0.f));
        }
    }
}

// ---------------------------------------------------------------------------
// GCN layer 2 fused (C=128), T-split: block = (node, T-half of 32 rows).
// Pipelined gather (2-deep) -> LDS -> 32x32x16 MFMA (K=128) -> relu -> h2.
// ---------------------------------------------------------------------------
__global__ __launch_bounds__(256) void gcn2_fused_kernel(
        const unsigned short* __restrict__ h, const unsigned short* __restrict__ Wt,
        const float* __restrict__ bias, unsigned short* __restrict__ out,
        const int* __restrict__ row_start, const int* __restrict__ csr_src,
        const float* __restrict__ csr_norm, const float* __restrict__ dinv) {
    constexpr int TC = TT * EMBC;         // full node elems
    constexpr int HC = 32 * EMBC;         // half-tile elems (4096)
    constexpr int STRIDE = EMBC + 8;      // 136
    __shared__ __align__(16) unsigned short sA[32 * STRIDE];
    __shared__ int s_src[256];
    __shared__ float s_w[256];

    const int n = blockIdx.x >> 1;
    const int half = blockIdx.x & 1;
    const int tid = threadIdx.x;
    const size_t hoff = (size_t)half * HC;

    int rs = row_start[n], re = row_start[n + 1];
    float dn = dinv[n];
    float selfw = dn * dn;
    const uint4* hn = (const uint4*)(h + (size_t)n * TC + hoff);
    float acc[2][8];
#pragma unroll
    for (int vv = 0; vv < 2; ++vv) {
        uint4 r = hn[tid + vv * 256];
        acc[vv][0] = selfw * bflo(r.x); acc[vv][1] = selfw * bfhi(r.x);
        acc[vv][2] = selfw * bflo(r.y); acc[vv][3] = selfw * bfhi(r.y);
        acc[vv][4] = selfw * bflo(r.z); acc[vv][5] = selfw * bfhi(r.z);
        acc[vv][6] = selfw * bflo(r.w); acc[vv][7] = selfw * bfhi(r.w);
    }
    for (int e0 = rs; e0 < re; e0 += 256) {
        int cnt = min(256, re - e0);
        if (tid < cnt) { s_src[tid] = csr_src[e0 + tid]; s_w[tid] = csr_norm[e0 + tid]; }
        __syncthreads();
        uint4 p0[2], p1[2];
        if (cnt > 0) {
            const uint4* hp = (const uint4*)(h + (size_t)s_src[0] * TC + hoff);
            p0[0] = hp[tid]; p0[1] = hp[tid + 256];
        }
        if (cnt > 1) {
            const uint4* hp = (const uint4*)(h + (size_t)s_src[1] * TC + hoff);
            p1[0] = hp[tid]; p1[1] = hp[tid + 256];
        }
        for (int j = 0; j < cnt; ++j) {
            uint4 c0 = (j & 1) ? p1[0] : p0[0];
            uint4 c1 = (j & 1) ? p1[1] : p0[1];
            float wgt = s_w[j];
            if (j + 2 < cnt) {
                const uint4* hp = (const uint4*)(h + (size_t)s_src[j + 2] * TC + hoff);
                if (j & 1) { p1[0] = hp[tid]; p1[1] = hp[tid + 256]; }
                else       { p0[0] = hp[tid]; p0[1] = hp[tid + 256]; }
            }
            acc[0][0] += wgt * bflo(c0.x); acc[0][1] += wgt * bfhi(c0.x);
            acc[0][2] += wgt * bflo(c0.y); acc[0][3] += wgt * bfhi(c0.y);
            acc[0][4] += wgt * bflo(c0.z); acc[0][5] += wgt * bfhi(c0.z);
            acc[0][6] += wgt * bflo(c0.w); acc[0][7] += wgt * bfhi(c0.w);
            acc[1][0] += wgt * bflo(c1.x); acc[1][1] += wgt * bfhi(c1.x);
            acc[1][2] += wgt * bflo(c1.y); acc[1][3] += wgt * bfhi(c1.y);
            acc[1][4] += wgt * bflo(c1.z); acc[1][5] += wgt * bfhi(c1.z);
            acc[1][6] += wgt * bflo(c1.w); acc[1][7] += wgt * bfhi(c1.w);
        }
        __syncthreads();
    }
    // write aggregated half-tile (32 x 128) to padded LDS
#pragma unroll
    for (int vv = 0; vv < 2; ++vv) {
        int f0 = (tid + vv * 256) * 8;
        int row = f0 >> 7, col = f0 & 127;
        uint4 r;
        r.x = (unsigned int)f2bf(acc[vv][0]) | ((unsigned int)f2bf(acc[vv][1]) << 16);
        r.y = (unsigned int)f2bf(acc[vv][2]) | ((unsigned int)f2bf(acc[vv][3]) << 16);
        r.z = (unsigned int)f2bf(acc[vv][4]) | ((unsigned int)f2bf(acc[vv][5]) << 16);
        r.w = (unsigned int)f2bf(acc[vv][6]) | ((unsigned int)f2bf(acc[vv][7]) << 16);
        *(uint4*)&sA[row * STRIDE + col] = r;
    }
    __syncthreads();

    // MFMA: (32x128) @ (128x128): wave ct -> col tile 32ct
    const int wave = tid >> 6;
    const int lane = tid & 63;
    const int l31 = lane & 31;
    const int q = lane >> 5;

    floatx16 accv = (floatx16)0.f;
#pragma unroll
    for (int kk = 0; kk < 8; ++kk) {
        short8 a = *(const short8*)&sA[l31 * STRIDE + kk * 16 + q * 8];
        short8 b = *(const short8*)(Wt + (size_t)(32 * wave + l31) * EMBC + kk * 16 + q * 8);
        accv = __builtin_amdgcn_mfma_f32_32x32x16_bf16(a, b, accv, 0, 0, 0);
    }
    unsigned short* orow = out + (size_t)n * (TT * 128) + (size_t)half * 32 * 128;
    int col = 32 * wave + l31;
    float bv = bias[col];
#pragma unroll
    for (int r = 0; r < 16; ++r) {
        int row = (r & 3) + 8 * (r >> 2) + 4 * q;
        orow[row * 128 + col] = f2bf(fmaxf(accv[r] + bv, 0.f));
    }
}

// ---------------------------------------------------------------------------
// conv2 as implicit-im2col 32x32x16 MFMA + bn2 + avgpool4 + relu, fused.
// Block = 2 nodes; wave = 32 t_out rows x 64 cols (2 independent acc chains).
// A staged in padded LDS (stride 136, +6 zero guard rows per node); B frags
// from global (L1/L2-cached, reused x2 per A frag, deep unrolled prefetch).
// ---------------------------------------------------------------------------
__global__ __launch_bounds__(256, 4) void conv2_mfma_kernel(
        const unsigned short* __restrict__ h2, const unsigned short* __restrict__ Bt,
        const float* __restrict__ g2, const float* __restrict__ b2,
        const float* __restrict__ m2, const float* __restrict__ v2,
        float* __restrict__ h3) {
    constexpr int STRIDE = 136;
    constexpr int NODESZ = 70 * STRIDE;                 // elems per node slot
    __shared__ __align__(16) unsigned short sA[2 * NODESZ];
    const int tid = threadIdx.x;

    // stage 2 nodes (64 rows x 128 each)
    const uint4* src = (const uint4*)(h2 + (size_t)blockIdx.x * 2 * (TT * EMBC));
#pragma unroll
    for (int it = 0; it < 8; ++it) {
        int idx = tid + it * 256;                       // uint4 index over 2048
        int node = idx >> 10;
        int f0 = (idx & 1023) * 8;
        int row = f0 >> 7, col = f0 & 127;
        *(uint4*)&sA[node * NODESZ + row * STRIDE + col] = src[idx];
    }
    // zero guard rows 64..69 of both nodes (2 x 6 x 128 elems = 192 uint4)
    if (tid < 192) {
        int node = tid / 96, jj = tid % 96;
        int row = 64 + jj / 16, col = (jj & 15) * 8;
        uint4 z; z.x = z.y = z.z = z.w = 0u;
        *(uint4*)&sA[node * NODESZ + row * STRIDE + col] = z;
    }
    __syncthreads();

    const int wave = tid >> 6;
    const int lane = tid & 63;
    const int l31 = lane & 31;
    const int q = lane >> 5;
    const int node = wave >> 1;
    const int rh = wave & 1;

    const unsigned short* sAn = &sA[node * NODESZ];
    const unsigned short* brow0 = Bt + (size_t)l31 * 896 + q * 8;
    const unsigned short* brow1 = Bt + (size_t)(32 + l31) * 896 + q * 8;

    floatx16 acc0 = (floatx16)0.f;
    floatx16 acc1 = (floatx16)0.f;
#pragma unroll
    for (int kw = 0; kw < 7; ++kw) {
#pragma unroll
        for (int kk = 0; kk < 8; ++kk) {
            short8 a = *(const short8*)&sAn[(32 * rh + l31 + kw) * STRIDE + kk * 16 + q * 8];
            short8 b0 = *(const short8*)(brow0 + kw * 128 + kk * 16);
            short8 b1 = *(const short8*)(brow1 + kw * 128 + kk * 16);
            acc0 = __builtin_amdgcn_mfma_f32_32x32x16_bf16(a, b0, acc0, 0, 0, 0);
            acc1 = __builtin_amdgcn_mfma_f32_32x32x16_bf16(a, b1, acc1, 0, 0, 0);
        }
    }
    // epilogue: regs 4j..4j+3 = rows (8j+4q+32rh)+{0..3} -> pool group 2j+q+8rh
    int n = blockIdx.x * 2 + node;
#pragma unroll
    for (int ct = 0; ct < 2; ++ct) {
        const floatx16& acc = ct ? acc1 : acc0;
        int col = 32 * ct + l31;
        float scale = g2[col] * rsqrtf(v2[col] + BNEPS);
        float mean = m2[col], beta = b2[col];
#pragma unroll
        for (int j = 0; j < 4; ++j) {
            int grp = 2 * j + q + 8 * rh;
            if (grp < 14) {
                float p = 0.25f * (acc[4 * j] + acc[4 * j + 1] + acc[4 * j + 2] + acc[4 * j + 3]);
                float val = (p - mean) * scale + beta;
                h3[((size_t)n * 14 + grp) * K1C + col] = fmaxf(val, 0.f);
            }
        }
    }
}

// ---------------------------------------------------------------------------
// Global mean pool per graph: h3 (N,14,64) -> g1 (B,14,64). batch = n/32.
// ---------------------------------------------------------------------------
__global__ void graph_pool_kernel(const float* __restrict__ h3, float* __restrict__ g1) {
    int b = blockIdx.x;
    for (int i = threadIdx.x; i < 14 * K1C; i += 256) {
        float acc = 0.f;
        for (int nn = 0; nn < 32; ++nn)
            acc += h3[((size_t)(b * 32 + nn)) * (14 * K1C) + i];
        g1[(size_t)b * (14 * K1C) + i] = acc * (1.f / 32.f);
    }
}

// ---------------------------------------------------------------------------
// Head: conv3 + bn3 + pool4 + relu + flatten + dense + log_softmax.
// ---------------------------------------------------------------------------
__global__ __launch_bounds__(256) void head_kernel(
        const float* __restrict__ g1, const float* __restrict__ w3,
        const float* __restrict__ g3, const float* __restrict__ b3,
        const float* __restrict__ m3, const float* __restrict__ v3,
        const float* __restrict__ dw, const float* __restrict__ db,
        float* __restrict__ out) {
    __shared__ float sg[14 * 64];
    __shared__ float sconv[8 * 64];
    __shared__ float sflat[128];
    __shared__ float slog[4];
    int b = blockIdx.x;
    int tid = threadIdx.x;
    for (int i = tid; i < 14 * 64; i += 256) sg[i] = g1[(size_t)b * (14 * 64) + i];
    __syncthreads();
    for (int i = tid; i < 8 * 64; i += 256) {
        int t = i >> 6, c = i & 63;
        float acc = 0.f;
        for (int k = 0; k < KSZ; ++k)
            for (int cin = 0; cin < 64; ++cin)
                acc += sg[(t + k) * 64 + cin] * w3[((size_t)(k * 64 + cin)) * 64 + c];
        sconv[i] = acc;
    }
    __syncthreads();
    for (int i = tid; i < 128; i += 256) {
        int j = i >> 6, c = i & 63;
        float p = 0.25f * (sconv[(4 * j + 0) * 64 + c] + sconv[(4 * j + 1) * 64 + c] +
                           sconv[(4 * j + 2) * 64 + c] + sconv[(4 * j + 3) * 64 + c]);
        float scale = g3[c] * rsqrtf(v3[c] + BNEPS);
        float val = (p - m3[c]) * scale + b3[c];
        sflat[i] = fmaxf(val, 0.f);
    }
    __syncthreads();
    if (tid < 4) {
        float acc = db[tid];
        for (int i = 0; i < 128; ++i) acc += sflat[i] * dw[i * 4 + tid];
        slog[tid] = acc;
    }
    __syncthreads();
    if (tid < 4) {
        float mx = fmaxf(fmaxf(slog[0], slog[1]), fmaxf(slog[2], slog[3]));
        float s = expf(slog[0] - mx) + expf(slog[1] - mx) +
                  expf(slog[2] - mx) + expf(slog[3] - mx);
        out[b * 4 + tid] = slog[tid] - mx - logf(s);
    }
}

// ---------------------------------------------------------------------------
extern "C" void kernel_launch(void* const* d_in, const int* in_sizes, int n_in,
                              void* d_out, int out_size, void* d_ws, size_t ws_size,
                              hipStream_t stream) {
    const float* x       = (const float*)d_in[0];
    const int*   ei      = (const int*)d_in[1];
    // d_in[2] = batch (arange//32, handled analytically)
    const float* conv1_w = (const float*)d_in[3];
    const float* bn1_g   = (const float*)d_in[4];
    const float* bn1_b   = (const float*)d_in[5];
    const float* bn1_m   = (const float*)d_in[6];
    const float* bn1_v   = (const float*)d_in[7];
    const float* gcn1_w  = (const float*)d_in[8];
    const float* gcn1_b  = (const float*)d_in[9];
    const float* gcn2_w  = (const float*)d_in[10];
    const float* gcn2_b  = (const float*)d_in[11];
    const float* conv2_w = (const float*)d_in[12];
    const float* bn2_g   = (const float*)d_in[13];
    const float* bn2_b   = (const float*)d_in[14];
    const float* bn2_m   = (const float*)d_in[15];
    const float* bn2_v   = (const float*)d_in[16];
    const float* conv3_w = (const float*)d_in[17];
    const float* bn3_g   = (const float*)d_in[18];
    const float* bn3_b   = (const float*)d_in[19];
    const float* bn3_m   = (const float*)d_in[20];
    const float* bn3_v   = (const float*)d_in[21];
    const float* dense_w = (const float*)d_in[22];
    const float* dense_b = (const float*)d_in[23];
    float* out = (float*)d_out;

    // Workspace layout (256B-aligned slots)
    char* ws = (char*)d_ws;
    size_t off = 0;
    auto alloc = [&](size_t bytes) { size_t o = off; off += (bytes + 255) & ~(size_t)255; return o; };
    size_t o_counters = alloc(2 * NN * sizeof(int));          // deg | cursor (zeroed)
    size_t o_rowstart = alloc((NN + 1) * sizeof(int));
    size_t o_csrsrc   = alloc(EE * sizeof(int));
    size_t o_csrnorm  = alloc(EE * sizeof(float));
    size_t o_dinv     = alloc(NN * sizeof(float));
    size_t o_wt1      = alloc(4096 * sizeof(unsigned short));
    size_t o_wt2      = alloc(16384 * sizeof(unsigned short));
    size_t o_bt       = alloc(57344 * sizeof(unsigned short));
    size_t o_h0       = alloc((size_t)NN * TT * K0C * sizeof(unsigned short));   // 8.4 MB
    size_t o_h1       = alloc((size_t)NN * TT * EMBC * sizeof(unsigned short));  // 33.5 MB
    size_t o_h2       = alloc((size_t)NN * TT * EMBC * sizeof(unsigned short));  // 33.5 MB
    size_t o_h3       = alloc((size_t)NN * 14 * K1C * sizeof(float));            // 7.3 MB
    size_t o_g1       = alloc((size_t)BB * 14 * K1C * sizeof(float));
    (void)alloc(4096); // slack

    int*   deg_i    = (int*)(ws + o_counters);
    int*   rowstart = (int*)(ws + o_rowstart);
    int*   csr_src  = (int*)(ws + o_csrsrc);
    float* csr_nrm  = (float*)(ws + o_csrnorm);
    float* dinv     = (float*)(ws + o_dinv);
    unsigned short* Wt1 = (unsigned short*)(ws + o_wt1);
    unsigned short* Wt2 = (unsigned short*)(ws + o_wt2);
    unsigned short* Bt  = (unsigned short*)(ws + o_bt);
    unsigned short* h0  = (unsigned short*)(ws + o_h0);
    unsigned short* h1  = (unsigned short*)(ws + o_h1);
    unsigned short* h2  = (unsigned short*)(ws + o_h2);
    float* h3 = (float*)(ws + o_h3);
    float* g1 = (float*)(ws + o_g1);
    int* cursor = deg_i + NN;

    hipMemsetAsync(deg_i, 0, 2 * NN * sizeof(int), stream);

    count_deg_kernel<<<EE / 256, 256, 0, stream>>>(ei, deg_i);
    dinv_kernel<<<NN / 256, 256, 0, stream>>>(deg_i, dinv);
    scan_kernel<<<1, 256, 0, stream>>>(deg_i, rowstart);
    fill_csr_kernel<<<EE / 256, 256, 0, stream>>>(ei, rowstart, cursor, dinv, csr_src, csr_nrm);
    prep_weights_kernel<<<304, 256, 0, stream>>>(gcn1_w, gcn2_w, conv2_w, Wt1, Wt2, Bt);

    conv1_bn_relu_kernel<<<(NN * TT * K0C) / 256, 256, 0, stream>>>(
        x, conv1_w, bn1_g, bn1_b, bn1_m, bn1_v, h0);

    gcn1_fused_kernel<<<NN, 256, 0, stream>>>(h0, Wt1, gcn1_b, h1,
                                              rowstart, csr_src, csr_nrm, dinv);
    gcn2_fused_kernel<<<NN * 2, 256, 0, stream>>>(h1, Wt2, gcn2_b, h2,
                                                  rowstart, csr_src, csr_nrm, dinv);

    conv2_mfma_kernel<<<NN / 2, 256, 0, stream>>>(h2, Bt, bn2_g, bn2_b, bn2_m, bn2_v, h3);
    graph_pool_kernel<<<BB, 256, 0, stream>>>(h3, g1);
    head_kernel<<<BB, 256, 0, stream>>>(g1, conv3_w, bn3_g, bn3_b, bn3_m, bn3_v,
                                        dense_w, dense_b, out);
}

// Round 5
// 247.579 us; speedup vs baseline: 2.3424x; 1.1443x over previous
//
#include <hip/hip_runtime.h>
#include <hip/hip_bf16.h>

// Problem constants (from reference)
#define NN 2048
#define TT 64
#define EE 16384
#define BB 64
#define K0C 32
#define EMBC 128
#define K1C 64
#define K2C 64
#define KSZ 7
#define POOLK 4
#define BNEPS 1e-5f

typedef __attribute__((ext_vector_type(8))) short short8;     // 8 bf16 (4 VGPRs)
typedef __attribute__((ext_vector_type(16))) float floatx16;  // 32x32 MFMA C/D frag

// float -> bf16 bits, round-to-nearest-even
static __device__ __forceinline__ unsigned short f2bf(float f) {
    unsigned int u = __float_as_uint(f);
    u += 0x7fffu + ((u >> 16) & 1u);
    return (unsigned short)(u >> 16);
}
static __device__ __forceinline__ float bflo(unsigned int u) { return __uint_as_float(u << 16); }
static __device__ __forceinline__ float bfhi(unsigned int u) { return __uint_as_float(u & 0xffff0000u); }

// ---------------------------------------------------------------------------
// Graph preprocessing
// ---------------------------------------------------------------------------
__global__ void count_deg_kernel(const int* __restrict__ ei, int* __restrict__ deg) {
    int e = blockIdx.x * 256 + threadIdx.x;
    if (e < EE) atomicAdd(&deg[ei[EE + e]], 1);   // dst = second row
}

__global__ void dinv_kernel(const int* __restrict__ deg, float* __restrict__ dinv) {
    int n = blockIdx.x * 256 + threadIdx.x;
    if (n < NN) dinv[n] = rsqrtf((float)deg[n] + 1.0f);   // +1 self loop
}

__global__ void scan_kernel(const int* __restrict__ deg, int* __restrict__ row_start) {
    __shared__ int tsum[256];
    int tid = threadIdx.x;
    int loc[8];
    int s = 0;
#pragma unroll
    for (int i = 0; i < 8; ++i) { loc[i] = s; s += deg[tid * 8 + i]; }
    tsum[tid] = s;
    __syncthreads();
    for (int off = 1; off < 256; off <<= 1) {
        int v = (tid >= off) ? tsum[tid - off] : 0;
        __syncthreads();
        tsum[tid] += v;
        __syncthreads();
    }
    int base = (tid > 0) ? tsum[tid - 1] : 0;
#pragma unroll
    for (int i = 0; i < 8; ++i) row_start[tid * 8 + i] = base + loc[i];
    if (tid == 255) row_start[NN] = tsum[255];
}

__global__ void fill_csr_kernel(const int* __restrict__ ei, const int* __restrict__ row_start,
                                int* __restrict__ cursor, const float* __restrict__ dinv,
                                int* __restrict__ csr_src, float* __restrict__ csr_norm) {
    int e = blockIdx.x * 256 + threadIdx.x;
    if (e >= EE) return;
    int s = ei[e];
    int d = ei[EE + e];
    int pos = row_start[d] + atomicAdd(&cursor[d], 1);
    csr_src[pos] = s;
    csr_norm[pos] = dinv[s] * dinv[d];
}

// ---------------------------------------------------------------------------
// Weight prep: transpose + cast to bf16.
//   Wt1[d][k] (128x32)  from gcn1_w (32,128)
//   Wt2[d][k] (128x128) from gcn2_w (128,128)
//   Bt [c][k] (64x896)  from conv2_w (7,128,64) with k = kw*128+cin
// ---------------------------------------------------------------------------
__global__ void prep_weights_kernel(const float* __restrict__ g1w, const float* __restrict__ g2w,
                                    const float* __restrict__ c2w,
                                    unsigned short* __restrict__ Wt1,
                                    unsigned short* __restrict__ Wt2,
                                    unsigned short* __restrict__ Bt) {
    int idx = blockIdx.x * 256 + threadIdx.x;
    if (idx < 4096) {
        int d = idx >> 5, k = idx & 31;
        Wt1[idx] = f2bf(g1w[k * 128 + d]);
    } else if (idx < 20480) {
        int j = idx - 4096;
        int d = j >> 7, k = j & 127;
        Wt2[j] = f2bf(g2w[k * 128 + d]);
    } else if (idx < 77824) {
        int j = idx - 20480;
        int c = j / 896, k = j % 896;
        Bt[j] = f2bf(c2w[k * 64 + c]);
    }
}

// ---------------------------------------------------------------------------
// conv1 (SAME, 1->32) + bn1 + relu : x (N,T) -> h0 bf16 (N,T,32)
// ---------------------------------------------------------------------------
__global__ void conv1_bn_relu_kernel(const float* __restrict__ x, const float* __restrict__ w,
                                     const float* __restrict__ g, const float* __restrict__ b,
                                     const float* __restrict__ m, const float* __restrict__ v,
                                     unsigned short* __restrict__ h0) {
    int idx = blockIdx.x * 256 + threadIdx.x;      // N*T*32 total
    int c = idx & 31;
    int t = (idx >> 5) & 63;
    int n = idx >> 11;
    float acc = 0.f;
#pragma unroll
    for (int k = 0; k < KSZ; ++k) {
        int tt = t + k - 3;
        if (tt >= 0 && tt < TT) acc += x[n * TT + tt] * w[k * K0C + c];
    }
    float scale = g[c] * rsqrtf(v[c] + BNEPS);
    float val = (acc - m[c]) * scale + b[c];
    h0[idx] = f2bf(fmaxf(val, 0.f));
}

// ---------------------------------------------------------------------------
// GCN layer 1 fused (C=32): pipelined gather-aggregate -> LDS -> 32x32x16
// MFMA (K=32) -> relu(+bias) -> h1 bf16 (N,T,128). One block per node.
// ---------------------------------------------------------------------------
__global__ __launch_bounds__(256) void gcn1_fused_kernel(
        const unsigned short* __restrict__ h, const unsigned short* __restrict__ Wt,
        const float* __restrict__ bias, unsigned short* __restrict__ out,
        const int* __restrict__ row_start, const int* __restrict__ csr_src,
        const float* __restrict__ csr_norm, const float* __restrict__ dinv) {
    constexpr int TC = TT * K0C;          // 2048 elems per node
    constexpr int STRIDE = K0C + 8;       // 40
    __shared__ __align__(16) unsigned short sA[TT * STRIDE];
    __shared__ int s_src[256];
    __shared__ float s_w[256];

    const int n = blockIdx.x;
    const int tid = threadIdx.x;

    int rs = row_start[n], re = row_start[n + 1];
    float dn = dinv[n];
    float selfw = dn * dn;
    const uint4* hn = (const uint4*)(h + (size_t)n * TC);
    float acc[8];
    {
        uint4 r = hn[tid];
        acc[0] = selfw * bflo(r.x); acc[1] = selfw * bfhi(r.x);
        acc[2] = selfw * bflo(r.y); acc[3] = selfw * bfhi(r.y);
        acc[4] = selfw * bflo(r.z); acc[5] = selfw * bfhi(r.z);
        acc[6] = selfw * bflo(r.w); acc[7] = selfw * bfhi(r.w);
    }
    for (int e0 = rs; e0 < re; e0 += 256) {
        int cnt = min(256, re - e0);
        if (tid < cnt) { s_src[tid] = csr_src[e0 + tid]; s_w[tid] = csr_norm[e0 + tid]; }
        __syncthreads();
        // 2-deep pipelined edge loop
        uint4 p0, p1;
        if (cnt > 0) p0 = ((const uint4*)(h + (size_t)s_src[0] * TC))[tid];
        if (cnt > 1) p1 = ((const uint4*)(h + (size_t)s_src[1] * TC))[tid];
        for (int j = 0; j < cnt; ++j) {
            uint4 r = (j & 1) ? p1 : p0;
            float wgt = s_w[j];
            if (j + 2 < cnt) {
                uint4 np = ((const uint4*)(h + (size_t)s_src[j + 2] * TC))[tid];
                if (j & 1) p1 = np; else p0 = np;
            }
            acc[0] += wgt * bflo(r.x); acc[1] += wgt * bfhi(r.x);
            acc[2] += wgt * bflo(r.y); acc[3] += wgt * bfhi(r.y);
            acc[4] += wgt * bflo(r.z); acc[5] += wgt * bfhi(r.z);
            acc[6] += wgt * bflo(r.w); acc[7] += wgt * bfhi(r.w);
        }
        __syncthreads();
    }
    // write aggregated tile to padded LDS
    {
        int f0 = tid * 8;
        int row = f0 >> 5, col = f0 & 31;
        uint4 r;
        r.x = (unsigned int)f2bf(acc[0]) | ((unsigned int)f2bf(acc[1]) << 16);
        r.y = (unsigned int)f2bf(acc[2]) | ((unsigned int)f2bf(acc[3]) << 16);
        r.z = (unsigned int)f2bf(acc[4]) | ((unsigned int)f2bf(acc[5]) << 16);
        r.w = (unsigned int)f2bf(acc[6]) | ((unsigned int)f2bf(acc[7]) << 16);
        *(uint4*)&sA[row * STRIDE + col] = r;
    }
    __syncthreads();

    // MFMA: (64x32) @ (32x128) -> 64x128
    const int wave = tid >> 6;
    const int lane = tid & 63;
    const int l31 = lane & 31;
    const int q = lane >> 5;
    const int rh = wave & 1;
    const int ch = wave >> 1;

    floatx16 accv[2];
    accv[0] = (floatx16)0.f;
    accv[1] = (floatx16)0.f;
#pragma unroll
    for (int kk = 0; kk < 2; ++kk) {
        short8 a = *(const short8*)&sA[(32 * rh + l31) * STRIDE + kk * 16 + q * 8];
#pragma unroll
        for (int ct = 0; ct < 2; ++ct) {
            short8 b = *(const short8*)(Wt + (size_t)(64 * ch + 32 * ct + l31) * K0C + kk * 16 + q * 8);
            accv[ct] = __builtin_amdgcn_mfma_f32_32x32x16_bf16(a, b, accv[ct], 0, 0, 0);
        }
    }
    unsigned short* orow = out + (size_t)n * (TT * 128);
#pragma unroll
    for (int ct = 0; ct < 2; ++ct) {
        int col = 64 * ch + 32 * ct + l31;
        float bv = bias[col];
#pragma unroll
        for (int r = 0; r < 16; ++r) {
            int row = (r & 3) + 8 * (r >> 2) + 4 * q + 32 * rh;
            orow[row * 128 + col] = f2bf(fmaxf(accv[ct][r] + bv, 0.f));
        }
    }
}

// ---------------------------------------------------------------------------
// GCN layer 2 fused (C=128), T-split: block = (node, T-half of 32 rows).
// Pipelined gather (2-deep) -> LDS -> 32x32x16 MFMA (K=128) -> relu -> h2.
// ---------------------------------------------------------------------------
__global__ __launch_bounds__(256) void gcn2_fused_kernel(
        const unsigned short* __restrict__ h, const unsigned short* __restrict__ Wt,
        const float* __restrict__ bias, unsigned short* __restrict__ out,
        const int* __restrict__ row_start, const int* __restrict__ csr_src,
        const float* __restrict__ csr_norm, const float* __restrict__ dinv) {
    constexpr int TC = TT * EMBC;         // full node elems
    constexpr int HC = 32 * EMBC;         // half-tile elems (4096)
    constexpr int STRIDE = EMBC + 8;      // 136
    __shared__ __align__(16) unsigned short sA[32 * STRIDE];
    __shared__ int s_src[256];
    __shared__ float s_w[256];

    const int n = blockIdx.x >> 1;
    const int half = blockIdx.x & 1;
    const int tid = threadIdx.x;
    const size_t hoff = (size_t)half * HC;

    int rs = row_start[n], re = row_start[n + 1];
    float dn = dinv[n];
    float selfw = dn * dn;
    const uint4* hn = (const uint4*)(h + (size_t)n * TC + hoff);
    float acc[2][8];
#pragma unroll
    for (int vv = 0; vv < 2; ++vv) {
        uint4 r = hn[tid + vv * 256];
        acc[vv][0] = selfw * bflo(r.x); acc[vv][1] = selfw * bfhi(r.x);
        acc[vv][2] = selfw * bflo(r.y); acc[vv][3] = selfw * bfhi(r.y);
        acc[vv][4] = selfw * bflo(r.z); acc[vv][5] = selfw * bfhi(r.z);
        acc[vv][6] = selfw * bflo(r.w); acc[vv][7] = selfw * bfhi(r.w);
    }
    for (int e0 = rs; e0 < re; e0 += 256) {
        int cnt = min(256, re - e0);
        if (tid < cnt) { s_src[tid] = csr_src[e0 + tid]; s_w[tid] = csr_norm[e0 + tid]; }
        __syncthreads();
        uint4 p0[2], p1[2];
        if (cnt > 0) {
            const uint4* hp = (const uint4*)(h + (size_t)s_src[0] * TC + hoff);
            p0[0] = hp[tid]; p0[1] = hp[tid + 256];
        }
        if (cnt > 1) {
            const uint4* hp = (const uint4*)(h + (size_t)s_src[1] * TC + hoff);
            p1[0] = hp[tid]; p1[1] = hp[tid + 256];
        }
        for (int j = 0; j < cnt; ++j) {
            uint4 c0 = (j & 1) ? p1[0] : p0[0];
            uint4 c1 = (j & 1) ? p1[1] : p0[1];
            float wgt = s_w[j];
            if (j + 2 < cnt) {
                const uint4* hp = (const uint4*)(h + (size_t)s_src[j + 2] * TC + hoff);
                if (j & 1) { p1[0] = hp[tid]; p1[1] = hp[tid + 256]; }
                else       { p0[0] = hp[tid]; p0[1] = hp[tid + 256]; }
            }
            acc[0][0] += wgt * bflo(c0.x); acc[0][1] += wgt * bfhi(c0.x);
            acc[0][2] += wgt * bflo(c0.y); acc[0][3] += wgt * bfhi(c0.y);
            acc[0][4] += wgt * bflo(c0.z); acc[0][5] += wgt * bfhi(c0.z);
            acc[0][6] += wgt * bflo(c0.w); acc[0][7] += wgt * bfhi(c0.w);
            acc[1][0] += wgt * bflo(c1.x); acc[1][1] += wgt * bfhi(c1.x);
            acc[1][2] += wgt * bflo(c1.y); acc[1][3] += wgt * bfhi(c1.y);
            acc[1][4] += wgt * bflo(c1.z); acc[1][5] += wgt * bfhi(c1.z);
            acc[1][6] += wgt * bflo(c1.w); acc[1][7] += wgt * bfhi(c1.w);
        }
        __syncthreads();
    }
    // write aggregated half-tile (32 x 128) to padded LDS
#pragma unroll
    for (int vv = 0; vv < 2; ++vv) {
        int f0 = (tid + vv * 256) * 8;
        int row = f0 >> 7, col = f0 & 127;
        uint4 r;
        r.x = (unsigned int)f2bf(acc[vv][0]) | ((unsigned int)f2bf(acc[vv][1]) << 16);
        r.y = (unsigned int)f2bf(acc[vv][2]) | ((unsigned int)f2bf(acc[vv][3]) << 16);
        r.z = (unsigned int)f2bf(acc[vv][4]) | ((unsigned int)f2bf(acc[vv][5]) << 16);
        r.w = (unsigned int)f2bf(acc[vv][6]) | ((unsigned int)f2bf(acc[vv][7]) << 16);
        *(uint4*)&sA[row * STRIDE + col] = r;
    }
    __syncthreads();

    // MFMA: (32x128) @ (128x128): wave ct -> col tile 32ct
    const int wave = tid >> 6;
    const int lane = tid & 63;
    const int l31 = lane & 31;
    const int q = lane >> 5;

    floatx16 accv = (floatx16)0.f;
#pragma unroll
    for (int kk = 0; kk < 8; ++kk) {
        short8 a = *(const short8*)&sA[l31 * STRIDE + kk * 16 + q * 8];
        short8 b = *(const short8*)(Wt + (size_t)(32 * wave + l31) * EMBC + kk * 16 + q * 8);
        accv = __builtin_amdgcn_mfma_f32_32x32x16_bf16(a, b, accv, 0, 0, 0);
    }
    unsigned short* orow = out + (size_t)n * (TT * 128) + (size_t)half * 32 * 128;
    int col = 32 * wave + l31;
    float bv = bias[col];
#pragma unroll
    for (int r = 0; r < 16; ++r) {
        int row = (r & 3) + 8 * (r >> 2) + 4 * q;
        orow[row * 128 + col] = f2bf(fmaxf(accv[r] + bv, 0.f));
    }
}

// ---------------------------------------------------------------------------
// conv2 as implicit-im2col 32x32x16 MFMA + bn2 + avgpool4 + relu, fused.
// Block = 2 nodes, 4 waves; wave = 32 t_out rows x 64 cols (2 acc chains).
// A staged in padded LDS; B (Bt slice per kw, 64x128 = 16 KB) staged in LDS
// double-buffered with register prefetch -> all MFMA operands come from LDS;
// all global loads are coalesced. One barrier per kw.
// ---------------------------------------------------------------------------
__global__ __launch_bounds__(256, 2) void conv2_mfma_kernel(
        const unsigned short* __restrict__ h2, const unsigned short* __restrict__ Bt,
        const float* __restrict__ g2, const float* __restrict__ b2,
        const float* __restrict__ m2, const float* __restrict__ v2,
        float* __restrict__ h3) {
    constexpr int STRIDE = 136;
    constexpr int NODESZ = 70 * STRIDE;                 // elems per node A slot
    constexpr int BSLOT = 64 * STRIDE;                  // elems per B buffer
    __shared__ __align__(16) unsigned short sA[2 * NODESZ];
    __shared__ __align__(16) unsigned short sB[2 * BSLOT];
    const int tid = threadIdx.x;

    // ---- stage A: 2 nodes (64 rows x 128 each), coalesced ----
    const uint4* src = (const uint4*)(h2 + (size_t)blockIdx.x * 2 * (TT * EMBC));
#pragma unroll
    for (int it = 0; it < 8; ++it) {
        int idx = tid + it * 256;                       // uint4 index over 2048
        int node = idx >> 10;
        int f0 = (idx & 1023) * 8;
        int row = f0 >> 7, col = f0 & 127;
        *(uint4*)&sA[node * NODESZ + row * STRIDE + col] = src[idx];
    }
    // zero guard rows 64..69 of both nodes
    if (tid < 192) {
        int node = tid / 96, jj = tid % 96;
        int row = 64 + jj / 16, col = (jj & 15) * 8;
        uint4 z; z.x = z.y = z.z = z.w = 0u;
        *(uint4*)&sA[node * NODESZ + row * STRIDE + col] = z;
    }
    // ---- stage B slice kw=0 (64 rows x 128 k), coalesced ----
    {
        int brow = tid >> 4, bcol = (tid & 15) * 8;     // 16 rows per 256-thread pass
#pragma unroll
        for (int it = 0; it < 4; ++it)
            *(uint4*)&sB[(brow + it * 16) * STRIDE + bcol] =
                *(const uint4*)(Bt + (size_t)(brow + it * 16) * 896 + bcol);
    }
    __syncthreads();

    const int wave = tid >> 6;
    const int lane = tid & 63;
    const int l31 = lane & 31;
    const int q = lane >> 5;
    const int node = wave >> 1;
    const int rh = wave & 1;

    const unsigned short* sAn = &sA[node * NODESZ];
    const int brow = tid >> 4, bcol = (tid & 15) * 8;

    floatx16 acc0 = (floatx16)0.f;
    floatx16 acc1 = (floatx16)0.f;
    uint4 breg[4];

    for (int kw = 0; kw < 7; ++kw) {
        // prefetch next B slice into registers (coalesced, overlaps compute)
        if (kw < 6) {
#pragma unroll
            for (int it = 0; it < 4; ++it)
                breg[it] = *(const uint4*)(Bt + (size_t)(brow + it * 16) * 896 +
                                           (kw + 1) * 128 + bcol);
        }
        const unsigned short* sBc = &sB[(kw & 1) * BSLOT];
#pragma unroll
        for (int kk = 0; kk < 8; ++kk) {
            short8 a = *(const short8*)&sAn[(32 * rh + l31 + kw) * STRIDE + kk * 16 + q * 8];
            short8 b0 = *(const short8*)&sBc[l31 * STRIDE + kk * 16 + q * 8];
            short8 b1 = *(const short8*)&sBc[(32 + l31) * STRIDE + kk * 16 + q * 8];
            acc0 = __builtin_amdgcn_mfma_f32_32x32x16_bf16(a, b0, acc0, 0, 0, 0);
            acc1 = __builtin_amdgcn_mfma_f32_32x32x16_bf16(a, b1, acc1, 0, 0, 0);
        }
        if (kw < 6) {
            unsigned short* sBn = &sB[((kw + 1) & 1) * BSLOT];
#pragma unroll
            for (int it = 0; it < 4; ++it)
                *(uint4*)&sBn[(brow + it * 16) * STRIDE + bcol] = breg[it];
            __syncthreads();
        }
    }
    // epilogue: regs 4j..4j+3 = rows (8j+4q+32rh)+{0..3} -> pool group 2j+q+8rh
    int n = blockIdx.x * 2 + node;
#pragma unroll
    for (int ct = 0; ct < 2; ++ct) {
        const floatx16& acc = ct ? acc1 : acc0;
        int col = 32 * ct + l31;
        float scale = g2[col] * rsqrtf(v2[col] + BNEPS);
        float mean = m2[col], beta = b2[col];
#pragma unroll
        for (int j = 0; j < 4; ++j) {
            int grp = 2 * j + q + 8 * rh;
            if (grp < 14) {
                float p = 0.25f * (acc[4 * j] + acc[4 * j + 1] + acc[4 * j + 2] + acc[4 * j + 3]);
                float val = (p - mean) * scale + beta;
                h3[((size_t)n * 14 + grp) * K1C + col] = fmaxf(val, 0.f);
            }
        }
    }
}

// ---------------------------------------------------------------------------
// Global mean pool per graph: h3 (N,14,64) -> g1 (B,14,64). batch = n/32.
// ---------------------------------------------------------------------------
__global__ void graph_pool_kernel(const float* __restrict__ h3, float* __restrict__ g1) {
    int b = blockIdx.x;
    for (int i = threadIdx.x; i < 14 * K1C; i += 256) {
        float acc = 0.f;
        for (int nn = 0; nn < 32; ++nn)
            acc += h3[((size_t)(b * 32 + nn)) * (14 * K1C) + i];
        g1[(size_t)b * (14 * K1C) + i] = acc * (1.f / 32.f);
    }
}

// ---------------------------------------------------------------------------
// Head: conv3 + bn3 + pool4 + relu + flatten + dense + log_softmax.
// ---------------------------------------------------------------------------
__global__ __launch_bounds__(256) void head_kernel(
        const float* __restrict__ g1, const float* __restrict__ w3,
        const float* __restrict__ g3, const float* __restrict__ b3,
        const float* __restrict__ m3, const float* __restrict__ v3,
        const float* __restrict__ dw, const float* __restrict__ db,
        float* __restrict__ out) {
    __shared__ float sg[14 * 64];
    __shared__ float sconv[8 * 64];
    __shared__ float sflat[128];
    __shared__ float slog[4];
    int b = blockIdx.x;
    int tid = threadIdx.x;
    for (int i = tid; i < 14 * 64; i += 256) sg[i] = g1[(size_t)b * (14 * 64) + i];
    __syncthreads();
    for (int i = tid; i < 8 * 64; i += 256) {
        int t = i >> 6, c = i & 63;
        float acc = 0.f;
        for (int k = 0; k < KSZ; ++k)
            for (int cin = 0; cin < 64; ++cin)
                acc += sg[(t + k) * 64 + cin] * w3[((size_t)(k * 64 + cin)) * 64 + c];
        sconv[i] = acc;
    }
    __syncthreads();
    for (int i = tid; i < 128; i += 256) {
        int j = i >> 6, c = i & 63;
        float p = 0.25f * (sconv[(4 * j + 0) * 64 + c] + sconv[(4 * j + 1) * 64 + c] +
                           sconv[(4 * j + 2) * 64 + c] + sconv[(4 * j + 3) * 64 + c]);
        float scale = g3[c] * rsqrtf(v3[c] + BNEPS);
        float val = (p - m3[c]) * scale + b3[c];
        sflat[i] = fmaxf(val, 0.f);
    }
    __syncthreads();
    if (tid < 4) {
        float acc = db[tid];
        for (int i = 0; i < 128; ++i) acc += sflat[i] * dw[i * 4 + tid];
        slog[tid] = acc;
    }
    __syncthreads();
    if (tid < 4) {
        float mx = fmaxf(fmaxf(slog[0], slog[1]), fmaxf(slog[2], slog[3]));
        float s = expf(slog[0] - mx) + expf(slog[1] - mx) +
                  expf(slog[2] - mx) + expf(slog[3] - mx);
        out[b * 4 + tid] = slog[tid] - mx - logf(s);
    }
}

// ---------------------------------------------------------------------------
extern "C" void kernel_launch(void* const* d_in, const int* in_sizes, int n_in,
                              void* d_out, int out_size, void* d_ws, size_t ws_size,
                              hipStream_t stream) {
    const float* x       = (const float*)d_in[0];
    const int*   ei      = (const int*)d_in[1];
    // d_in[2] = batch (arange//32, handled analytically)
    const float* conv1_w = (const float*)d_in[3];
    const float* bn1_g   = (const float*)d_in[4];
    const float* bn1_b   = (const float*)d_in[5];
    const float* bn1_m   = (const float*)d_in[6];
    const float* bn1_v   = (const float*)d_in[7];
    const float* gcn1_w  = (const float*)d_in[8];
    const float* gcn1_b  = (const float*)d_in[9];
    const float* gcn2_w  = (const float*)d_in[10];
    const float* gcn2_b  = (const float*)d_in[11];
    const float* conv2_w = (const float*)d_in[12];
    const float* bn2_g   = (const float*)d_in[13];
    const float* bn2_b   = (const float*)d_in[14];
    const float* bn2_m   = (const float*)d_in[15];
    const float* bn2_v   = (const float*)d_in[16];
    const float* conv3_w = (const float*)d_in[17];
    const float* bn3_g   = (const float*)d_in[18];
    const float* bn3_b   = (const float*)d_in[19];
    const float* bn3_m   = (const float*)d_in[20];
    const float* bn3_v   = (const float*)d_in[21];
    const float* dense_w = (const float*)d_in[22];
    const float* dense_b = (const float*)d_in[23];
    float* out = (float*)d_out;

    // Workspace layout (256B-aligned slots)
    char* ws = (char*)d_ws;
    size_t off = 0;
    auto alloc = [&](size_t bytes) { size_t o = off; off += (bytes + 255) & ~(size_t)255; return o; };
    size_t o_counters = alloc(2 * NN * sizeof(int));          // deg | cursor (zeroed)
    size_t o_rowstart = alloc((NN + 1) * sizeof(int));
    size_t o_csrsrc   = alloc(EE * sizeof(int));
    size_t o_csrnorm  = alloc(EE * sizeof(float));
    size_t o_dinv     = alloc(NN * sizeof(float));
    size_t o_wt1      = alloc(4096 * sizeof(unsigned short));
    size_t o_wt2      = alloc(16384 * sizeof(unsigned short));
    size_t o_bt       = alloc(57344 * sizeof(unsigned short));
    size_t o_h0       = alloc((size_t)NN * TT * K0C * sizeof(unsigned short));   // 8.4 MB
    size_t o_h1       = alloc((size_t)NN * TT * EMBC * sizeof(unsigned short));  // 33.5 MB
    size_t o_h2       = alloc((size_t)NN * TT * EMBC * sizeof(unsigned short));  // 33.5 MB
    size_t o_h3       = alloc((size_t)NN * 14 * K1C * sizeof(float));            // 7.3 MB
    size_t o_g1       = alloc((size_t)BB * 14 * K1C * sizeof(float));
    (void)alloc(4096); // slack

    int*   deg_i    = (int*)(ws + o_counters);
    int*   rowstart = (int*)(ws + o_rowstart);
    int*   csr_src  = (int*)(ws + o_csrsrc);
    float* csr_nrm  = (float*)(ws + o_csrnorm);
    float* dinv     = (float*)(ws + o_dinv);
    unsigned short* Wt1 = (unsigned short*)(ws + o_wt1);
    unsigned short* Wt2 = (unsigned short*)(ws + o_wt2);
    unsigned short* Bt  = (unsigned short*)(ws + o_bt);
    unsigned short* h0  = (unsigned short*)(ws + o_h0);
    unsigned short* h1  = (unsigned short*)(ws + o_h1);
    unsigned short* h2  = (unsigned short*)(ws + o_h2);
    float* h3 = (float*)(ws + o_h3);
    float* g1 = (float*)(ws + o_g1);
    int* cursor = deg_i + NN;

    hipMemsetAsync(deg_i, 0, 2 * NN * sizeof(int), stream);

    count_deg_kernel<<<EE / 256, 256, 0, stream>>>(ei, deg_i);
    dinv_kernel<<<NN / 256, 256, 0, stream>>>(deg_i, dinv);
    scan_kernel<<<1, 256, 0, stream>>>(deg_i, rowstart);
    fill_csr_kernel<<<EE / 256, 256, 0, stream>>>(ei, rowstart, cursor, dinv, csr_src, csr_nrm);
    prep_weights_kernel<<<304, 256, 0, stream>>>(gcn1_w, gcn2_w, conv2_w, Wt1, Wt2, Bt);

    conv1_bn_relu_kernel<<<(NN * TT * K0C) / 256, 256, 0, stream>>>(
        x, conv1_w, bn1_g, bn1_b, bn1_m, bn1_v, h0);

    gcn1_fused_kernel<<<NN, 256, 0, stream>>>(h0, Wt1, gcn1_b, h1,
                                              rowstart, csr_src, csr_nrm, dinv);
    gcn2_fused_kernel<<<NN * 2, 256, 0, stream>>>(h1, Wt2, gcn2_b, h2,
                                                  rowstart, csr_src, csr_nrm, dinv);

    conv2_mfma_kernel<<<NN / 2, 256, 0, stream>>>(h2, Bt, bn2_g, bn2_b, bn2_m, bn2_v, h3);
    graph_pool_kernel<<<BB, 256, 0, stream>>>(h3, g1);
    head_kernel<<<BB, 256, 0, stream>>>(g1, conv3_w, bn3_g, bn3_b, bn3_m, bn3_v,
                                        dense_w, dense_b, out);
}

// Round 6
// 235.690 us; speedup vs baseline: 2.4605x; 1.0504x over previous
//
#include <hip/hip_runtime.h>
#include <hip/hip_bf16.h>

// Problem constants (from reference)
#define NN 2048
#define TT 64
#define EE 16384
#define BB 64
#define K0C 32
#define EMBC 128
#define K1C 64
#define K2C 64
#define KSZ 7
#define POOLK 4
#define BNEPS 1e-5f

typedef __attribute__((ext_vector_type(8))) short short8;     // 8 bf16 (4 VGPRs)
typedef __attribute__((ext_vector_type(16))) float floatx16;  // 32x32 MFMA C/D frag

// float -> bf16 bits, round-to-nearest-even
static __device__ __forceinline__ unsigned short f2bf(float f) {
    unsigned int u = __float_as_uint(f);
    u += 0x7fffu + ((u >> 16) & 1u);
    return (unsigned short)(u >> 16);
}
static __device__ __forceinline__ float bflo(unsigned int u) { return __uint_as_float(u << 16); }
static __device__ __forceinline__ float bfhi(unsigned int u) { return __uint_as_float(u & 0xffff0000u); }

static __device__ __forceinline__ void unpack8(uint4 r, float w, float* acc) {
    acc[0] += w * bflo(r.x); acc[1] += w * bfhi(r.x);
    acc[2] += w * bflo(r.y); acc[3] += w * bfhi(r.y);
    acc[4] += w * bflo(r.z); acc[5] += w * bfhi(r.z);
    acc[6] += w * bflo(r.w); acc[7] += w * bfhi(r.w);
}
static __device__ __forceinline__ uint4 pack8(const float* a) {
    uint4 r;
    r.x = (unsigned int)f2bf(a[0]) | ((unsigned int)f2bf(a[1]) << 16);
    r.y = (unsigned int)f2bf(a[2]) | ((unsigned int)f2bf(a[3]) << 16);
    r.z = (unsigned int)f2bf(a[4]) | ((unsigned int)f2bf(a[5]) << 16);
    r.w = (unsigned int)f2bf(a[6]) | ((unsigned int)f2bf(a[7]) << 16);
    return r;
}

// ---------------------------------------------------------------------------
// Graph preprocessing
// ---------------------------------------------------------------------------
__global__ void count_deg_kernel(const int* __restrict__ ei, int* __restrict__ deg) {
    int e = blockIdx.x * 256 + threadIdx.x;
    if (e < EE) atomicAdd(&deg[ei[EE + e]], 1);   // dst = second row
}

__global__ void dinv_kernel(const int* __restrict__ deg, float* __restrict__ dinv) {
    int n = blockIdx.x * 256 + threadIdx.x;
    if (n < NN) dinv[n] = rsqrtf((float)deg[n] + 1.0f);   // +1 self loop
}

__global__ void scan_kernel(const int* __restrict__ deg, int* __restrict__ row_start) {
    __shared__ int tsum[256];
    int tid = threadIdx.x;
    int loc[8];
    int s = 0;
#pragma unroll
    for (int i = 0; i < 8; ++i) { loc[i] = s; s += deg[tid * 8 + i]; }
    tsum[tid] = s;
    __syncthreads();
    for (int off = 1; off < 256; off <<= 1) {
        int v = (tid >= off) ? tsum[tid - off] : 0;
        __syncthreads();
        tsum[tid] += v;
        __syncthreads();
    }
    int base = (tid > 0) ? tsum[tid - 1] : 0;
#pragma unroll
    for (int i = 0; i < 8; ++i) row_start[tid * 8 + i] = base + loc[i];
    if (tid == 255) row_start[NN] = tsum[255];
}

__global__ void fill_csr_kernel(const int* __restrict__ ei, const int* __restrict__ row_start,
                                int* __restrict__ cursor, const float* __restrict__ dinv,
                                int* __restrict__ csr_src, float* __restrict__ csr_norm) {
    int e = blockIdx.x * 256 + threadIdx.x;
    if (e >= EE) return;
    int s = ei[e];
    int d = ei[EE + e];
    int pos = row_start[d] + atomicAdd(&cursor[d], 1);
    csr_src[pos] = s;
    csr_norm[pos] = dinv[s] * dinv[d];
}

// ---------------------------------------------------------------------------
// Weight prep: transpose + cast to bf16.
// ---------------------------------------------------------------------------
__global__ void prep_weights_kernel(const float* __restrict__ g1w, const float* __restrict__ g2w,
                                    const float* __restrict__ c2w,
                                    unsigned short* __restrict__ Wt1,
                                    unsigned short* __restrict__ Wt2,
                                    unsigned short* __restrict__ Bt) {
    int idx = blockIdx.x * 256 + threadIdx.x;
    if (idx < 4096) {
        int d = idx >> 5, k = idx & 31;
        Wt1[idx] = f2bf(g1w[k * 128 + d]);
    } else if (idx < 20480) {
        int j = idx - 4096;
        int d = j >> 7, k = j & 127;
        Wt2[j] = f2bf(g2w[k * 128 + d]);
    } else if (idx < 77824) {
        int j = idx - 20480;
        int c = j / 896, k = j % 896;
        Bt[j] = f2bf(c2w[k * 64 + c]);
    }
}

// ---------------------------------------------------------------------------
// conv1 (SAME, 1->32) + bn1 + relu : x (N,T) -> h0t bf16 (T, N, 32)
// (transposed layout: per-t slice is 128 KB -> L2-resident for gcn1 gather)
// ---------------------------------------------------------------------------
__global__ void conv1_bn_relu_kernel(const float* __restrict__ x, const float* __restrict__ w,
                                     const float* __restrict__ g, const float* __restrict__ b,
                                     const float* __restrict__ m, const float* __restrict__ v,
                                     unsigned short* __restrict__ h0t) {
    int idx = blockIdx.x * 256 + threadIdx.x;      // (t*2048 + n)*32 + c
    int c = idx & 31;
    int n = (idx >> 5) & 2047;
    int t = idx >> 16;
    float acc = 0.f;
#pragma unroll
    for (int k = 0; k < KSZ; ++k) {
        int tt = t + k - 3;
        if (tt >= 0 && tt < TT) acc += x[n * TT + tt] * w[k * K0C + c];
    }
    float scale = g[c] * rsqrtf(v[c] + BNEPS);
    float val = (acc - m[c]) * scale + b[c];
    h0t[idx] = f2bf(fmaxf(val, 0.f));              // coalesced in (T,N,32)
}

// ---------------------------------------------------------------------------
// GCN layer 1, t-sliced: block = (t, 128 dst nodes). Gather from the L2-hot
// 128 KB h0t slice (2 threads/dst, fp32 acc) -> LDS -> (128x32)@(32x128)
// MFMA -> relu(+bias) -> h1t (T, N, 128). XCD swizzle: blockIdx&7 picks the
// XCD-local t range so each slice is pulled into one XCD's L2 only.
// ---------------------------------------------------------------------------
__global__ __launch_bounds__(256) void gcn1_t_kernel(
        const unsigned short* __restrict__ h0t, const unsigned short* __restrict__ Wt,
        const float* __restrict__ bias, unsigned short* __restrict__ h1t,
        const int* __restrict__ row_start, const int* __restrict__ csr_src,
        const float* __restrict__ csr_norm, const float* __restrict__ dinv) {
    constexpr int STRIDE = 40;
    __shared__ __align__(16) unsigned short sAgg[128 * STRIDE];
    const int b = blockIdx.x;                 // 1024 blocks = 64 t x 16 groups
    const int xcd = b & 7;
    const int idx = b >> 3;                   // 0..127
    const int t = xcd * 8 + (idx >> 4);       // slice-major within XCD
    const int g = idx & 15;
    const int n0 = g * 128;
    const int tid = threadIdx.x;
    const int sub = tid >> 1;                 // dst 0..127
    const int half = tid & 1;                 // 16-channel half
    const int n = n0 + sub;

    const unsigned short* base = h0t + (size_t)t * (NN * K0C);
    int rs = row_start[n], re = row_start[n + 1];
    float dn = dinv[n];
    float selfw = dn * dn;
    float acc[16];
    {
        const uint4* p = (const uint4*)(base + n * K0C + half * 16);
        uint4 r0 = p[0], r1 = p[1];
#pragma unroll
        for (int i = 0; i < 16; ++i) acc[i] = 0.f;
        unpack8(r0, selfw, acc); unpack8(r1, selfw, acc + 8);
    }
    for (int e = rs; e < re; ++e) {
        int src = csr_src[e];
        float wgt = csr_norm[e];
        const uint4* p = (const uint4*)(base + src * K0C + half * 16);
        uint4 r0 = p[0], r1 = p[1];
        unpack8(r0, wgt, acc); unpack8(r1, wgt, acc + 8);
    }
    *(uint4*)&sAgg[sub * STRIDE + half * 16] = pack8(acc);
    *(uint4*)&sAgg[sub * STRIDE + half * 16 + 8] = pack8(acc + 8);
    __syncthreads();

    // MFMA (128x32)@(32x128): wave = 32 rows, 4 col-tiles
    const int wave = tid >> 6;
    const int lane = tid & 63;
    const int l31 = lane & 31;
    const int q = lane >> 5;
    floatx16 accv[4];
#pragma unroll
    for (int ct = 0; ct < 4; ++ct) accv[ct] = (floatx16)0.f;
#pragma unroll
    for (int kk = 0; kk < 2; ++kk) {
        short8 a = *(const short8*)&sAgg[(32 * wave + l31) * STRIDE + kk * 16 + q * 8];
#pragma unroll
        for (int ct = 0; ct < 4; ++ct) {
            short8 bb = *(const short8*)(Wt + (size_t)(32 * ct + l31) * K0C + kk * 16 + q * 8);
            accv[ct] = __builtin_amdgcn_mfma_f32_32x32x16_bf16(a, bb, accv[ct], 0, 0, 0);
        }
    }
    unsigned short* orow = h1t + ((size_t)t * NN + n0) * EMBC;
#pragma unroll
    for (int ct = 0; ct < 4; ++ct) {
        int col = 32 * ct + l31;
        float bv = bias[col];
#pragma unroll
        for (int r = 0; r < 16; ++r) {
            int row = 32 * wave + (r & 3) + 8 * (r >> 2) + 4 * q;
            orow[row * EMBC + col] = f2bf(fmaxf(accv[ct][r] + bv, 0.f));
        }
    }
}

// ---------------------------------------------------------------------------
// GCN layer 2, t-sliced: block = (t, 32 dst nodes). Gather from the L2-hot
// 512 KB h1t slice (8 threads/dst, fp32 acc) -> LDS -> (32x128)@(128x128)
// MFMA -> relu(+bias) -> h2 (N, T, 128) node-major via LDS-staged stores.
// ---------------------------------------------------------------------------
__global__ __launch_bounds__(256) void gcn2_t_kernel(
        const unsigned short* __restrict__ h1t, const unsigned short* __restrict__ Wt,
        const float* __restrict__ bias, unsigned short* __restrict__ h2,
        const int* __restrict__ row_start, const int* __restrict__ csr_src,
        const float* __restrict__ csr_norm, const float* __restrict__ dinv) {
    constexpr int STRIDE = 136;
    __shared__ __align__(16) unsigned short sAgg[32 * STRIDE];
    const int b = blockIdx.x;                 // 4096 blocks = 64 t x 64 groups
    const int xcd = b & 7;
    const int idx = b >> 3;                   // 0..511
    const int t = xcd * 8 + (idx >> 6);       // slice-major within XCD
    const int g = idx & 63;
    const int n0 = g * 32;
    const int tid = threadIdx.x;
    const int sub = tid >> 3;                 // dst 0..31
    const int part = tid & 7;                 // 16-channel part
    const int n = n0 + sub;

    const unsigned short* base = h1t + (size_t)t * (NN * EMBC);
    int rs = row_start[n], re = row_start[n + 1];
    float dn = dinv[n];
    float selfw = dn * dn;
    float acc[16];
    {
        const uint4* p = (const uint4*)(base + n * EMBC + part * 16);
        uint4 r0 = p[0], r1 = p[1];
#pragma unroll
        for (int i = 0; i < 16; ++i) acc[i] = 0.f;
        unpack8(r0, selfw, acc); unpack8(r1, selfw, acc + 8);
    }
    for (int e = rs; e < re; ++e) {
        int src = csr_src[e];
        float wgt = csr_norm[e];
        const uint4* p = (const uint4*)(base + src * EMBC + part * 16);
        uint4 r0 = p[0], r1 = p[1];
        unpack8(r0, wgt, acc); unpack8(r1, wgt, acc + 8);
    }
    *(uint4*)&sAgg[sub * STRIDE + part * 16] = pack8(acc);
    *(uint4*)&sAgg[sub * STRIDE + part * 16 + 8] = pack8(acc + 8);
    __syncthreads();

    // MFMA (32x128)@(128x128): wave ct -> col tile 32ct
    const int wave = tid >> 6;
    const int lane = tid & 63;
    const int l31 = lane & 31;
    const int q = lane >> 5;
    floatx16 accv = (floatx16)0.f;
#pragma unroll
    for (int kk = 0; kk < 8; ++kk) {
        short8 a = *(const short8*)&sAgg[l31 * STRIDE + kk * 16 + q * 8];
        short8 bb = *(const short8*)(Wt + (size_t)(32 * wave + l31) * EMBC + kk * 16 + q * 8);
        accv = __builtin_amdgcn_mfma_f32_32x32x16_bf16(a, bb, accv, 0, 0, 0);
    }
    __syncthreads();                          // all sAgg reads done
    {
        int col = 32 * wave + l31;
        float bv = bias[col];
#pragma unroll
        for (int r = 0; r < 16; ++r) {
            int row = (r & 3) + 8 * (r >> 2) + 4 * q;
            sAgg[row * STRIDE + col] = f2bf(fmaxf(accv[r] + bv, 0.f));
        }
    }
    __syncthreads();
    // coalesced store: thread -> (node, 16-ch chunk), 32 B each
    {
        const uint4* sp = (const uint4*)&sAgg[(tid >> 3) * STRIDE + (tid & 7) * 16];
        uint4* dp = (uint4*)(h2 + ((size_t)(n0 + (tid >> 3)) * TT + t) * EMBC + (tid & 7) * 16);
        dp[0] = sp[0];
        dp[1] = sp[1];
    }
}

// ---------------------------------------------------------------------------
// conv2 as implicit-im2col 32x32x16 MFMA + bn2 + avgpool4 + relu, fused.
// Block = 2 nodes, 4 waves; A in padded LDS; B double-buffered in LDS.
// ---------------------------------------------------------------------------
__global__ __launch_bounds__(256, 2) void conv2_mfma_kernel(
        const unsigned short* __restrict__ h2, const unsigned short* __restrict__ Bt,
        const float* __restrict__ g2, const float* __restrict__ b2,
        const float* __restrict__ m2, const float* __restrict__ v2,
        float* __restrict__ h3) {
    constexpr int STRIDE = 136;
    constexpr int NODESZ = 70 * STRIDE;
    constexpr int BSLOT = 64 * STRIDE;
    __shared__ __align__(16) unsigned short sA[2 * NODESZ];
    __shared__ __align__(16) unsigned short sB[2 * BSLOT];
    const int tid = threadIdx.x;

    const uint4* src = (const uint4*)(h2 + (size_t)blockIdx.x * 2 * (TT * EMBC));
#pragma unroll
    for (int it = 0; it < 8; ++it) {
        int idx = tid + it * 256;
        int node = idx >> 10;
        int f0 = (idx & 1023) * 8;
        int row = f0 >> 7, col = f0 & 127;
        *(uint4*)&sA[node * NODESZ + row * STRIDE + col] = src[idx];
    }
    if (tid < 192) {
        int node = tid / 96, jj = tid % 96;
        int row = 64 + jj / 16, col = (jj & 15) * 8;
        uint4 z; z.x = z.y = z.z = z.w = 0u;
        *(uint4*)&sA[node * NODESZ + row * STRIDE + col] = z;
    }
    {
        int brow = tid >> 4, bcol = (tid & 15) * 8;
#pragma unroll
        for (int it = 0; it < 4; ++it)
            *(uint4*)&sB[(brow + it * 16) * STRIDE + bcol] =
                *(const uint4*)(Bt + (size_t)(brow + it * 16) * 896 + bcol);
    }
    __syncthreads();

    const int wave = tid >> 6;
    const int lane = tid & 63;
    const int l31 = lane & 31;
    const int q = lane >> 5;
    const int node = wave >> 1;
    const int rh = wave & 1;

    const unsigned short* sAn = &sA[node * NODESZ];
    const int brow = tid >> 4, bcol = (tid & 15) * 8;

    floatx16 acc0 = (floatx16)0.f;
    floatx16 acc1 = (floatx16)0.f;
    uint4 breg[4];

    for (int kw = 0; kw < 7; ++kw) {
        if (kw < 6) {
#pragma unroll
            for (int it = 0; it < 4; ++it)
                breg[it] = *(const uint4*)(Bt + (size_t)(brow + it * 16) * 896 +
                                           (kw + 1) * 128 + bcol);
        }
        const unsigned short* sBc = &sB[(kw & 1) * BSLOT];
#pragma unroll
        for (int kk = 0; kk < 8; ++kk) {
            short8 a = *(const short8*)&sAn[(32 * rh + l31 + kw) * STRIDE + kk * 16 + q * 8];
            short8 b0 = *(const short8*)&sBc[l31 * STRIDE + kk * 16 + q * 8];
            short8 b1 = *(const short8*)&sBc[(32 + l31) * STRIDE + kk * 16 + q * 8];
            acc0 = __builtin_amdgcn_mfma_f32_32x32x16_bf16(a, b0, acc0, 0, 0, 0);
            acc1 = __builtin_amdgcn_mfma_f32_32x32x16_bf16(a, b1, acc1, 0, 0, 0);
        }
        if (kw < 6) {
            unsigned short* sBn = &sB[((kw + 1) & 1) * BSLOT];
#pragma unroll
            for (int it = 0; it < 4; ++it)
                *(uint4*)&sBn[(brow + it * 16) * STRIDE + bcol] = breg[it];
            __syncthreads();
        }
    }
    int n = blockIdx.x * 2 + node;
#pragma unroll
    for (int ct = 0; ct < 2; ++ct) {
        const floatx16& acc = ct ? acc1 : acc0;
        int col = 32 * ct + l31;
        float scale = g2[col] * rsqrtf(v2[col] + BNEPS);
        float mean = m2[col], beta = b2[col];
#pragma unroll
        for (int j = 0; j < 4; ++j) {
            int grp = 2 * j + q + 8 * rh;
            if (grp < 14) {
                float p = 0.25f * (acc[4 * j] + acc[4 * j + 1] + acc[4 * j + 2] + acc[4 * j + 3]);
                float val = (p - mean) * scale + beta;
                h3[((size_t)n * 14 + grp) * K1C + col] = fmaxf(val, 0.f);
            }
        }
    }
}

// ---------------------------------------------------------------------------
// Global mean pool per graph: h3 (N,14,64) -> g1 (B,14,64). batch = n/32.
// ---------------------------------------------------------------------------
__global__ void graph_pool_kernel(const float* __restrict__ h3, float* __restrict__ g1) {
    int b = blockIdx.x;
    for (int i = threadIdx.x; i < 14 * K1C; i += 256) {
        float acc = 0.f;
        for (int nn = 0; nn < 32; ++nn)
            acc += h3[((size_t)(b * 32 + nn)) * (14 * K1C) + i];
        g1[(size_t)b * (14 * K1C) + i] = acc * (1.f / 32.f);
    }
}

// ---------------------------------------------------------------------------
// Head: conv3 + bn3 + pool4 + relu + flatten + dense + log_softmax.
// ---------------------------------------------------------------------------
__global__ __launch_bounds__(256) void head_kernel(
        const float* __restrict__ g1, const float* __restrict__ w3,
        const float* __restrict__ g3, const float* __restrict__ b3,
        const float* __restrict__ m3, const float* __restrict__ v3,
        const float* __restrict__ dw, const float* __restrict__ db,
        float* __restrict__ out) {
    __shared__ float sg[14 * 64];
    __shared__ float sconv[8 * 64];
    __shared__ float sflat[128];
    __shared__ float slog[4];
    int b = blockIdx.x;
    int tid = threadIdx.x;
    for (int i = tid; i < 14 * 64; i += 256) sg[i] = g1[(size_t)b * (14 * 64) + i];
    __syncthreads();
    for (int i = tid; i < 8 * 64; i += 256) {
        int t = i >> 6, c = i & 63;
        float acc = 0.f;
        for (int k = 0; k < KSZ; ++k)
            for (int cin = 0; cin < 64; ++cin)
                acc += sg[(t + k) * 64 + cin] * w3[((size_t)(k * 64 + cin)) * 64 + c];
        sconv[i] = acc;
    }
    __syncthreads();
    for (int i = tid; i < 128; i += 256) {
        int j = i >> 6, c = i & 63;
        float p = 0.25f * (sconv[(4 * j + 0) * 64 + c] + sconv[(4 * j + 1) * 64 + c] +
                           sconv[(4 * j + 2) * 64 + c] + sconv[(4 * j + 3) * 64 + c]);
        float scale = g3[c] * rsqrtf(v3[c] + BNEPS);
        float val = (p - m3[c]) * scale + b3[c];
        sflat[i] = fmaxf(val, 0.f);
    }
    __syncthreads();
    if (tid < 4) {
        float acc = db[tid];
        for (int i = 0; i < 128; ++i) acc += sflat[i] * dw[i * 4 + tid];
        slog[tid] = acc;
    }
    __syncthreads();
    if (tid < 4) {
        float mx = fmaxf(fmaxf(slog[0], slog[1]), fmaxf(slog[2], slog[3]));
        float s = expf(slog[0] - mx) + expf(slog[1] - mx) +
                  expf(slog[2] - mx) + expf(slog[3] - mx);
        out[b * 4 + tid] = slog[tid] - mx - logf(s);
    }
}

// ---------------------------------------------------------------------------
extern "C" void kernel_launch(void* const* d_in, const int* in_sizes, int n_in,
                              void* d_out, int out_size, void* d_ws, size_t ws_size,
                              hipStream_t stream) {
    const float* x       = (const float*)d_in[0];
    const int*   ei      = (const int*)d_in[1];
    // d_in[2] = batch (arange//32, handled analytically)
    const float* conv1_w = (const float*)d_in[3];
    const float* bn1_g   = (const float*)d_in[4];
    const float* bn1_b   = (const float*)d_in[5];
    const float* bn1_m   = (const float*)d_in[6];
    const float* bn1_v   = (const float*)d_in[7];
    const float* gcn1_w  = (const float*)d_in[8];
    const float* gcn1_b  = (const float*)d_in[9];
    const float* gcn2_w  = (const float*)d_in[10];
    const float* gcn2_b  = (const float*)d_in[11];
    const float* conv2_w = (const float*)d_in[12];
    const float* bn2_g   = (const float*)d_in[13];
    const float* bn2_b   = (const float*)d_in[14];
    const float* bn2_m   = (const float*)d_in[15];
    const float* bn2_v   = (const float*)d_in[16];
    const float* conv3_w = (const float*)d_in[17];
    const float* bn3_g   = (const float*)d_in[18];
    const float* bn3_b   = (const float*)d_in[19];
    const float* bn3_m   = (const float*)d_in[20];
    const float* bn3_v   = (const float*)d_in[21];
    const float* dense_w = (const float*)d_in[22];
    const float* dense_b = (const float*)d_in[23];
    float* out = (float*)d_out;

    // Workspace layout (256B-aligned slots)
    char* ws = (char*)d_ws;
    size_t off = 0;
    auto alloc = [&](size_t bytes) { size_t o = off; off += (bytes + 255) & ~(size_t)255; return o; };
    size_t o_counters = alloc(2 * NN * sizeof(int));          // deg | cursor (zeroed)
    size_t o_rowstart = alloc((NN + 1) * sizeof(int));
    size_t o_csrsrc   = alloc(EE * sizeof(int));
    size_t o_csrnorm  = alloc(EE * sizeof(float));
    size_t o_dinv     = alloc(NN * sizeof(float));
    size_t o_wt1      = alloc(4096 * sizeof(unsigned short));
    size_t o_wt2      = alloc(16384 * sizeof(unsigned short));
    size_t o_bt       = alloc(57344 * sizeof(unsigned short));
    size_t o_h0       = alloc((size_t)NN * TT * K0C * sizeof(unsigned short));   // h0t (T,N,32)
    size_t o_h1       = alloc((size_t)NN * TT * EMBC * sizeof(unsigned short));  // h1t (T,N,128)
    size_t o_h2       = alloc((size_t)NN * TT * EMBC * sizeof(unsigned short));  // h2 (N,T,128)
    size_t o_h3       = alloc((size_t)NN * 14 * K1C * sizeof(float));
    size_t o_g1       = alloc((size_t)BB * 14 * K1C * sizeof(float));
    (void)alloc(4096); // slack

    int*   deg_i    = (int*)(ws + o_counters);
    int*   rowstart = (int*)(ws + o_rowstart);
    int*   csr_src  = (int*)(ws + o_csrsrc);
    float* csr_nrm  = (float*)(ws + o_csrnorm);
    float* dinv     = (float*)(ws + o_dinv);
    unsigned short* Wt1 = (unsigned short*)(ws + o_wt1);
    unsigned short* Wt2 = (unsigned short*)(ws + o_wt2);
    unsigned short* Bt  = (unsigned short*)(ws + o_bt);
    unsigned short* h0t = (unsigned short*)(ws + o_h0);
    unsigned short* h1t = (unsigned short*)(ws + o_h1);
    unsigned short* h2  = (unsigned short*)(ws + o_h2);
    float* h3 = (float*)(ws + o_h3);
    float* g1 = (float*)(ws + o_g1);
    int* cursor = deg_i + NN;

    hipMemsetAsync(deg_i, 0, 2 * NN * sizeof(int), stream);

    count_deg_kernel<<<EE / 256, 256, 0, stream>>>(ei, deg_i);
    dinv_kernel<<<NN / 256, 256, 0, stream>>>(deg_i, dinv);
    scan_kernel<<<1, 256, 0, stream>>>(deg_i, rowstart);
    fill_csr_kernel<<<EE / 256, 256, 0, stream>>>(ei, rowstart, cursor, dinv, csr_src, csr_nrm);
    prep_weights_kernel<<<304, 256, 0, stream>>>(gcn1_w, gcn2_w, conv2_w, Wt1, Wt2, Bt);

    conv1_bn_relu_kernel<<<(NN * TT * K0C) / 256, 256, 0, stream>>>(
        x, conv1_w, bn1_g, bn1_b, bn1_m, bn1_v, h0t);

    gcn1_t_kernel<<<64 * 16, 256, 0, stream>>>(h0t, Wt1, gcn1_b, h1t,
                                               rowstart, csr_src, csr_nrm, dinv);
    gcn2_t_kernel<<<64 * 64, 256, 0, stream>>>(h1t, Wt2, gcn2_b, h2,
                                               rowstart, csr_src, csr_nrm, dinv);

    conv2_mfma_kernel<<<NN / 2, 256, 0, stream>>>(h2, Bt, bn2_g, bn2_b, bn2_m, bn2_v, h3);
    graph_pool_kernel<<<BB, 256, 0, stream>>>(h3, g1);
    head_kernel<<<BB, 256, 0, stream>>>(g1, conv3_w, bn3_g, bn3_b, bn3_m, bn3_v,
                                        dense_w, dense_b, out);
}